// Round 1
// baseline (1611.551 us; speedup 1.0000x reference)
//
#include <hip/hip_runtime.h>
#include <math.h>

// ---- problem constants ----
constexpr int N_  = 2048;
constexpr int T_  = 1024;
constexpr int E_  = 16384;
constexpr int B_  = 32;
constexpr int C1_ = 8,  C2_ = 16, C3_ = 32;
constexpr int K1_ = 25, K2_ = 15, K3_ = 7;
constexpr int L2_ = 252;          // conv2+pool output length
constexpr int T2_ = 61;           // conv3+pool output length
constexpr int D_  = 128;
constexpr float EPS_ = 1e-5f;
constexpr int M2_ = K2_ + 3;      // 18 combined taps (conv2 fused with pool4)
constexpr int M3_ = K3_ + 3;      // 10 combined taps (conv3 fused with pool4)
constexpr int H3E_ = T2_ * C3_;   // 1952 elems per node after conv stack
constexpr int HGE_ = T2_ * D_;    // 7808 elems per node in GCN feature space

// ======================= positional MLP =======================
__global__ void k_pe(const float* __restrict__ pos, const float* __restrict__ w1,
                     const float* __restrict__ b1, const float* __restrict__ w2,
                     const float* __restrict__ b2, float* __restrict__ pe) {
    __shared__ float hid[8][32];
    int tid = threadIdx.x;
    int c = tid & 31, nl = tid >> 5;
    int n = blockIdx.x * 8 + nl;
    float p0 = pos[n * 3 + 0], p1 = pos[n * 3 + 1], p2 = pos[n * 3 + 2];
    float h = fmaxf(p0 * w1[c] + p1 * w1[32 + c] + p2 * w1[64 + c] + b1[c], 0.f);
    hid[nl][c] = h;
    __syncthreads();
    float o = b2[c];
#pragma unroll
    for (int cc = 0; cc < 32; ++cc) o += hid[nl][cc] * w2[cc * 32 + c];
    pe[n * 32 + c] = o;
}

// ======================= conv1 + bn1 + relu =======================
__global__ void k_conv1(const float* __restrict__ x, const float* __restrict__ w,
                        const float* __restrict__ cb, const float* __restrict__ g,
                        const float* __restrict__ bt, float* __restrict__ h1) {
    __shared__ float xs[256 + K1_ - 1];   // 280
    __shared__ float wl[C1_ * K1_];       // 200
    __shared__ float cl[C1_];
    int bid = blockIdx.x;
    int n = bid >> 2;
    int t0 = (bid & 3) * 256;
    int tid = threadIdx.x;
    for (int i = tid; i < 256 + K1_ - 1; i += 256) {
        int gi = t0 - (K1_ / 2) + i;
        xs[i] = (gi >= 0 && gi < T_) ? x[n * T_ + gi] : 0.f;
    }
    for (int i = tid; i < C1_ * K1_; i += 256) {
        int c = i / K1_;
        wl[i] = w[i] * (g[c] * rsqrtf(1.f + EPS_));
    }
    if (tid < C1_) cl[tid] = cb[tid] * (g[tid] * rsqrtf(1.f + EPS_)) + bt[tid];
    __syncthreads();
#pragma unroll
    for (int c = 0; c < C1_; ++c) {
        float acc = cl[c];
#pragma unroll
        for (int k = 0; k < K1_; ++k) acc += wl[c * K1_ + k] * xs[tid + k];
        h1[(n * C1_ + c) * T_ + t0 + tid] = fmaxf(acc, 0.f);
    }
}

// ========== conv2 + bn2 + avgpool4 + relu (fused 18-tap filter) ==========
__global__ void k_conv2(const float* __restrict__ h1, const float* __restrict__ w,
                        const float* __restrict__ cb, const float* __restrict__ g,
                        const float* __restrict__ bt, float* __restrict__ h2) {
    __shared__ float xs[C1_ * T_];         // 8192 floats (32 KB)
    __shared__ float wl[C2_ * C1_ * M2_];  // 2304
    __shared__ float cl[C2_];
    int n = blockIdx.x, tid = threadIdx.x;
    const float4* s4 = (const float4*)(h1 + (size_t)n * C1_ * T_);
    float4* d4 = (float4*)xs;
    for (int i = tid; i < C1_ * T_ / 4; i += 256) d4[i] = s4[i];
    for (int i = tid; i < C2_ * C1_ * M2_; i += 256) {
        int c2 = i / (C1_ * M2_);
        int r = i % (C1_ * M2_);
        int c1 = r / M2_, m = r % M2_;
        float s = 0.f;
        for (int k = 0; k < K2_; ++k)
            if (m - k >= 0 && m - k <= 3) s += w[(c2 * C1_ + c1) * K2_ + k];
        wl[i] = s * (g[c2] * rsqrtf(1.f + EPS_)) * 0.25f;
    }
    if (tid < C2_) cl[tid] = cb[tid] * (g[tid] * rsqrtf(1.f + EPS_)) + bt[tid];
    __syncthreads();
    for (int i = tid; i < C2_ * L2_; i += 256) {
        int c2 = i / L2_, p = i % L2_;
        float acc = cl[c2];
        const float* wp = &wl[c2 * C1_ * M2_];
#pragma unroll
        for (int c1 = 0; c1 < C1_; ++c1) {
            const float* xp = &xs[c1 * T_ + 4 * p];
#pragma unroll
            for (int m = 0; m < M2_; ++m) acc += wp[c1 * M2_ + m] * xp[m];
        }
        h2[(size_t)n * C2_ * L2_ + i] = fmaxf(acc, 0.f);
    }
}

// ==== conv3 + bn3 + avgpool4 + relu + add pe, output transposed [n][t][c] ====
__global__ void k_conv3(const float* __restrict__ h2, const float* __restrict__ w,
                        const float* __restrict__ cb, const float* __restrict__ g,
                        const float* __restrict__ bt, const float* __restrict__ pe,
                        float* __restrict__ h3) {
    __shared__ float xs[C2_ * L2_];        // 4032
    __shared__ float wl[C3_ * C2_ * M3_];  // 5120
    __shared__ float cl[C3_], pl[C3_];
    int n = blockIdx.x, tid = threadIdx.x;
    const float4* s4 = (const float4*)(h2 + (size_t)n * C2_ * L2_);
    float4* d4 = (float4*)xs;
    for (int i = tid; i < C2_ * L2_ / 4; i += 256) d4[i] = s4[i];
    for (int i = tid; i < C3_ * C2_ * M3_; i += 256) {
        int c3 = i / (C2_ * M3_);
        int r = i % (C2_ * M3_);
        int c2 = r / M3_, m = r % M3_;
        float sv = 0.f;
        for (int k = 0; k < K3_; ++k)
            if (m - k >= 0 && m - k <= 3) sv += w[(c3 * C2_ + c2) * K3_ + k];
        wl[i] = sv * (g[c3] * rsqrtf(1.f + EPS_)) * 0.25f;
    }
    if (tid < C3_) {
        cl[tid] = cb[tid] * (g[tid] * rsqrtf(1.f + EPS_)) + bt[tid];
        pl[tid] = pe[n * C3_ + tid];
    }
    __syncthreads();
    for (int i = tid; i < T2_ * C3_; i += 256) {
        int t = i >> 5, c = i & 31;
        float acc = cl[c];
        const float* wp = &wl[c * C2_ * M3_];
#pragma unroll
        for (int c2 = 0; c2 < C2_; ++c2) {
            const float* xp = &xs[c2 * L2_ + 4 * t];
#pragma unroll
            for (int m = 0; m < M3_; ++m) acc += wp[c2 * M3_ + m] * xp[m];
        }
        h3[(size_t)n * H3E_ + i] = fmaxf(acc, 0.f) + pl[c];
    }
}

// ======================= graph CSR build =======================
__global__ void k_count(const int* __restrict__ ei, int* __restrict__ count) {
    int e = blockIdx.x * 256 + threadIdx.x;
    if (e < E_) atomicAdd(&count[ei[E_ + e]], 1);
}

__global__ void k_scan(const int* __restrict__ count, int* __restrict__ off,
                       float* __restrict__ dinv) {
    __shared__ int part[256];
    int tid = threadIdx.x;
    int loc[8];
    int s = 0;
    int base = tid * 8;
#pragma unroll
    for (int j = 0; j < 8; ++j) { loc[j] = count[base + j]; s += loc[j]; }
    part[tid] = s;
    __syncthreads();
    for (int o = 1; o < 256; o <<= 1) {
        int add = (tid >= o) ? part[tid - o] : 0;
        __syncthreads();
        part[tid] += add;
        __syncthreads();
    }
    int run = part[tid] - s;  // exclusive prefix
#pragma unroll
    for (int j = 0; j < 8; ++j) {
        off[base + j] = run;
        run += loc[j];
        dinv[base + j] = rsqrtf((float)(loc[j] + 1));  // +1 self loop
    }
}

__global__ void k_fill(const int* __restrict__ ei, const int* __restrict__ off,
                       int* __restrict__ cur, int* __restrict__ csr) {
    int e = blockIdx.x * 256 + threadIdx.x;
    if (e < E_) {
        int d = ei[E_ + e];
        int p = atomicAdd(&cur[d], 1);
        csr[off[d] + p] = ei[e];
    }
}

// =================== degree-normalized aggregation (gather) ===================
template <int NE4, int R>
__global__ void k_agg(const float* __restrict__ h, const int* __restrict__ off,
                      const int* __restrict__ cnt, const int* __restrict__ csr,
                      const float* __restrict__ dinv, float* __restrict__ out) {
    int n = blockIdx.x, tid = threadIdx.x;
    float4 acc[R];
    const float4* self = (const float4*)(h + (size_t)n * NE4 * 4);
    float dn = dinv[n];
#pragma unroll
    for (int r = 0; r < R; ++r) {
        int q = tid + 256 * r;
        if (q < NE4) {
            float4 v = self[q];
            acc[r].x = v.x * dn; acc[r].y = v.y * dn; acc[r].z = v.z * dn; acc[r].w = v.w * dn;
        }
    }
    int st = off[n], c = cnt[n];
    for (int i = 0; i < c; ++i) {
        int sn = csr[st + i];
        float f = dinv[sn];
        const float4* row = (const float4*)(h + (size_t)sn * NE4 * 4);
#pragma unroll
        for (int r = 0; r < R; ++r) {
            int q = tid + 256 * r;
            if (q < NE4) {
                float4 v = row[q];
                acc[r].x += f * v.x; acc[r].y += f * v.y; acc[r].z += f * v.z; acc[r].w += f * v.w;
            }
        }
    }
    float4* o = (float4*)(out + (size_t)n * NE4 * 4);
#pragma unroll
    for (int r = 0; r < R; ++r) {
        int q = tid + 256 * r;
        if (q < NE4) o[q] = acc[r];
    }
}

// ============ GCN layer 1 GEMM: (61x32)@(32x128), *dinv, +b, relu ============
__global__ void k_gemm1(const float* __restrict__ agg, const float* __restrict__ W,
                        const float* __restrict__ bias, const float* __restrict__ dinv,
                        float* __restrict__ out) {
    __shared__ float row[H3E_];      // 1952
    __shared__ float wl[C3_ * D_];   // 4096
    __shared__ float bl[D_];
    int n = blockIdx.x, tid = threadIdx.x;
    {
        const float4* s = (const float4*)(agg + (size_t)n * H3E_);
        float4* d4 = (float4*)row;
        for (int q = tid; q < H3E_ / 4; q += 256) d4[q] = s[q];
        const float4* ws = (const float4*)W;
        float4* wd = (float4*)wl;
        for (int q = tid; q < C3_ * D_ / 4; q += 256) wd[q] = ws[q];
        if (tid < D_) bl[tid] = bias[tid];
    }
    __syncthreads();
    float dn = dinv[n];
#pragma unroll
    for (int r = 0; r < 8; ++r) {
        int q = tid + 256 * r;
        if (q < T2_ * D_ / 4) {
            int t = q / (D_ / 4);
            int d0 = (q % (D_ / 4)) * 4;
            float4 acc = make_float4(0.f, 0.f, 0.f, 0.f);
            const float* rp = &row[t * C3_];
#pragma unroll
            for (int c = 0; c < C3_; ++c) {
                float rv = rp[c];
                float4 wv = *(const float4*)&wl[c * D_ + d0];
                acc.x += rv * wv.x; acc.y += rv * wv.y; acc.z += rv * wv.z; acc.w += rv * wv.w;
            }
            float4 bv = *(const float4*)&bl[d0];
            acc.x = fmaxf(acc.x * dn + bv.x, 0.f);
            acc.y = fmaxf(acc.y * dn + bv.y, 0.f);
            acc.z = fmaxf(acc.z * dn + bv.z, 0.f);
            acc.w = fmaxf(acc.w * dn + bv.w, 0.f);
            *(float4*)&out[(size_t)n * HGE_ + q * 4] = acc;
        }
    }
}

// ===== GCN layer 2 GEMM: (61x128)@(128x128), *dinv, +b, relu, in-place =====
__global__ void k_gemm2(float* __restrict__ agg, const float* __restrict__ W,
                        const float* __restrict__ bias, const float* __restrict__ dinv) {
    __shared__ float row[HGE_];     // 7808 floats (31.2 KB)
    __shared__ float wl[32 * D_];   // 4096 floats (16 KB chunk of W)
    __shared__ float bl[D_];
    int n = blockIdx.x, tid = threadIdx.x;
    {
        const float4* s = (const float4*)(agg + (size_t)n * HGE_);
        float4* d4 = (float4*)row;
        for (int q = tid; q < HGE_ / 4; q += 256) d4[q] = s[q];
        if (tid < D_) bl[tid] = bias[tid];
    }
    float4 acc[8];
#pragma unroll
    for (int r = 0; r < 8; ++r) acc[r] = make_float4(0.f, 0.f, 0.f, 0.f);
    for (int ck = 0; ck < 4; ++ck) {
        __syncthreads();
        const float4* ws = (const float4*)(W + ck * 32 * D_);
        float4* wd = (float4*)wl;
        for (int q = tid; q < 32 * D_ / 4; q += 256) wd[q] = ws[q];
        __syncthreads();
#pragma unroll
        for (int r = 0; r < 8; ++r) {
            int q = tid + 256 * r;
            if (q < T2_ * D_ / 4) {
                int t = q / (D_ / 4);
                int d0 = (q % (D_ / 4)) * 4;
                const float* rp = &row[t * D_ + ck * 32];
#pragma unroll
                for (int c = 0; c < 32; ++c) {
                    float rv = rp[c];
                    float4 wv = *(const float4*)&wl[c * D_ + d0];
                    acc[r].x += rv * wv.x; acc[r].y += rv * wv.y;
                    acc[r].z += rv * wv.z; acc[r].w += rv * wv.w;
                }
            }
        }
    }
    float dn = dinv[n];
#pragma unroll
    for (int r = 0; r < 8; ++r) {
        int q = tid + 256 * r;
        if (q < T2_ * D_ / 4) {
            int d0 = (q % (D_ / 4)) * 4;
            float4 bv = *(const float4*)&bl[d0];
            float4 v = acc[r];
            v.x = fmaxf(v.x * dn + bv.x, 0.f);
            v.y = fmaxf(v.y * dn + bv.y, 0.f);
            v.z = fmaxf(v.z * dn + bv.z, 0.f);
            v.w = fmaxf(v.w * dn + bv.w, 0.f);
            *(float4*)&agg[(size_t)n * HGE_ + q * 4] = v;
        }
    }
}

// ================= batch mean-pool (sums; divide in final) =================
__global__ void k_cnt(const int* __restrict__ batch, int* __restrict__ cnt) {
    int n = blockIdx.x * 256 + threadIdx.x;
    if (n < N_) atomicAdd(&cnt[batch[n]], 1);
}

__global__ void k_pool(const float* __restrict__ hg2, const int* __restrict__ batch,
                       float* __restrict__ pooled) {
    __shared__ float accum[B_ * D_];  // 4096 floats
    int t = blockIdx.x;               // 0..60
    int chunk = blockIdx.y;           // 0..7
    int d = threadIdx.x;              // 0..127
    for (int i = threadIdx.x; i < B_ * D_; i += 128) accum[i] = 0.f;
    __syncthreads();
    int n0 = chunk * 256;
    for (int n = n0; n < n0 + 256; ++n) {
        float v = hg2[(size_t)n * HGE_ + t * D_ + d];
        accum[batch[n] * D_ + d] += v;
    }
    __syncthreads();
    for (int b = 0; b < B_; ++b)
        atomicAdd(&pooled[(size_t)b * HGE_ + d * T2_ + t], accum[b * D_ + d]);
}

// ============== dense (7808x4) + log_softmax, one block per batch ==============
__global__ void k_final(const float* __restrict__ pooled, const int* __restrict__ cnt,
                        const float* __restrict__ dw, const float* __restrict__ db,
                        float* __restrict__ out) {
    __shared__ float red[4][256];
    int b = blockIdx.x, tid = threadIdx.x;
    float inv = 1.f / fmaxf((float)cnt[b], 1.f);
    float a0 = 0.f, a1 = 0.f, a2 = 0.f, a3 = 0.f;
    const float4* dw4 = (const float4*)dw;
    for (int f = tid; f < HGE_; f += 256) {
        float v = pooled[(size_t)b * HGE_ + f] * inv;
        float4 w = dw4[f];
        a0 += v * w.x; a1 += v * w.y; a2 += v * w.z; a3 += v * w.w;
    }
    red[0][tid] = a0; red[1][tid] = a1; red[2][tid] = a2; red[3][tid] = a3;
    __syncthreads();
    for (int off = 128; off > 0; off >>= 1) {
        if (tid < off)
            for (int j = 0; j < 4; ++j) red[j][tid] += red[j][tid + off];
        __syncthreads();
    }
    if (tid == 0) {
        float l[4];
        for (int j = 0; j < 4; ++j) l[j] = red[j][0] + db[j];
        float m = fmaxf(fmaxf(l[0], l[1]), fmaxf(l[2], l[3]));
        float s = expf(l[0] - m) + expf(l[1] - m) + expf(l[2] - m) + expf(l[3] - m);
        float ls = m + logf(s);
        for (int j = 0; j < 4; ++j) out[b * 4 + j] = l[j] - ls;
    }
}

// ======================= launch =======================
extern "C" void kernel_launch(void* const* d_in, const int* in_sizes, int n_in,
                              void* d_out, int out_size, void* d_ws, size_t ws_size,
                              hipStream_t stream) {
    const float* x       = (const float*)d_in[0];
    const float* pos     = (const float*)d_in[1];
    const float* conv1_w = (const float*)d_in[2];
    const float* conv1_b = (const float*)d_in[3];
    const float* bn1_g   = (const float*)d_in[4];
    const float* bn1_b   = (const float*)d_in[5];
    const float* conv2_w = (const float*)d_in[6];
    const float* conv2_b = (const float*)d_in[7];
    const float* bn2_g   = (const float*)d_in[8];
    const float* bn2_b   = (const float*)d_in[9];
    const float* conv3_w = (const float*)d_in[10];
    const float* conv3_b = (const float*)d_in[11];
    const float* bn3_g   = (const float*)d_in[12];
    const float* bn3_b   = (const float*)d_in[13];
    const float* pos_w1  = (const float*)d_in[14];
    const float* pos_b1  = (const float*)d_in[15];
    const float* pos_w2  = (const float*)d_in[16];
    const float* pos_b2  = (const float*)d_in[17];
    const float* gcn1_w  = (const float*)d_in[18];
    const float* gcn1_b  = (const float*)d_in[19];
    const float* gcn2_w  = (const float*)d_in[20];
    const float* gcn2_b  = (const float*)d_in[21];
    const float* dense_w = (const float*)d_in[22];
    const float* dense_b = (const float*)d_in[23];
    const int*   eidx    = (const int*)d_in[24];
    const int*   batch   = (const int*)d_in[25];
    float* out = (float*)d_out;
    char* ws = (char*)d_ws;

    // workspace layout
    size_t o_h1     = 0;                                          // 64 MB (reused as hg1)
    size_t o_h2     = o_h1 + (size_t)N_ * C1_ * T_ * 4;           // 33 MB
    size_t o_h3     = o_h2 + (size_t)N_ * C2_ * L2_ * 4;          // 16 MB
    size_t o_pe     = o_h3 + (size_t)N_ * H3E_ * 4;
    size_t o_agg1   = o_pe + (size_t)N_ * C3_ * 4;                // 16 MB
    size_t o_agg2   = o_agg1 + (size_t)N_ * H3E_ * 4;             // 64 MB (gemm2 in-place)
    size_t o_pooled = o_agg2 + (size_t)N_ * HGE_ * 4;             // 1 MB
    size_t o_count  = o_pooled + (size_t)B_ * HGE_ * 4;
    size_t o_off    = o_count + (size_t)N_ * 4;
    size_t o_cur    = o_off + (size_t)N_ * 4;
    size_t o_dinv   = o_cur + (size_t)N_ * 4;
    size_t o_csr    = o_dinv + (size_t)N_ * 4;
    size_t o_cnt    = o_csr + (size_t)E_ * 4;

    float* h1     = (float*)(ws + o_h1);
    float* h2     = (float*)(ws + o_h2);
    float* h3     = (float*)(ws + o_h3);
    float* pe     = (float*)(ws + o_pe);
    float* agg1   = (float*)(ws + o_agg1);
    float* agg2   = (float*)(ws + o_agg2);
    float* pooled = (float*)(ws + o_pooled);
    int*   count  = (int*)(ws + o_count);
    int*   offs   = (int*)(ws + o_off);
    int*   cur    = (int*)(ws + o_cur);
    float* dinv   = (float*)(ws + o_dinv);
    int*   csr    = (int*)(ws + o_csr);
    int*   cnt    = (int*)(ws + o_cnt);
    float* hg1    = h1;  // reuse

    hipMemsetAsync(count, 0, (size_t)N_ * 4, stream);
    hipMemsetAsync(cur, 0, (size_t)N_ * 4, stream);
    hipMemsetAsync(cnt, 0, (size_t)B_ * 4, stream);
    hipMemsetAsync(pooled, 0, (size_t)B_ * HGE_ * 4, stream);

    k_pe<<<N_ / 8, 256, 0, stream>>>(pos, pos_w1, pos_b1, pos_w2, pos_b2, pe);
    k_conv1<<<N_ * 4, 256, 0, stream>>>(x, conv1_w, conv1_b, bn1_g, bn1_b, h1);
    k_conv2<<<N_, 256, 0, stream>>>(h1, conv2_w, conv2_b, bn2_g, bn2_b, h2);
    k_conv3<<<N_, 256, 0, stream>>>(h2, conv3_w, conv3_b, bn3_g, bn3_b, pe, h3);

    k_count<<<E_ / 256, 256, 0, stream>>>(eidx, count);
    k_scan<<<1, 256, 0, stream>>>(count, offs, dinv);
    k_fill<<<E_ / 256, 256, 0, stream>>>(eidx, offs, cur, csr);
    k_cnt<<<N_ / 256, 256, 0, stream>>>(batch, cnt);

    k_agg<488, 2><<<N_, 256, 0, stream>>>(h3, offs, count, csr, dinv, agg1);
    k_gemm1<<<N_, 256, 0, stream>>>(agg1, gcn1_w, gcn1_b, dinv, hg1);
    k_agg<1952, 8><<<N_, 256, 0, stream>>>(hg1, offs, count, csr, dinv, agg2);
    k_gemm2<<<N_, 256, 0, stream>>>(agg2, gcn2_w, gcn2_b, dinv);

    k_pool<<<dim3(T2_, 8), 128, 0, stream>>>(agg2, batch, pooled);
    k_final<<<B_, 256, 0, stream>>>(pooled, cnt, dense_w, dense_b, out);
}

// Round 2
// 525.196 us; speedup vs baseline: 3.0685x; 3.0685x over previous
//
#include <hip/hip_runtime.h>
#include <math.h>

// ---- problem constants ----
constexpr int N_  = 2048;
constexpr int T_  = 1024;
constexpr int E_  = 16384;
constexpr int B_  = 32;
constexpr int C1_ = 8,  C2_ = 16, C3_ = 32;
constexpr int K1_ = 25, K2_ = 15, K3_ = 7;
constexpr int T2_ = 61;           // conv3+pool output length
constexpr int D_  = 128;
constexpr float EPS_ = 1e-5f;
constexpr int M2_ = K2_ + 3;      // 18 fused taps (conv2 ⊗ pool4)
constexpr int M3_ = K3_ + 3;      // 10 fused taps (conv3 ⊗ pool4)
constexpr int H3E_ = T2_ * C3_;   // 1952 elems/node after conv stack
constexpr int HGE_ = T2_ * D_;    // 7808 elems/node in GCN space
constexpr int M_   = N_ * T2_;    // 124928 flattened GEMM rows (= 976*128)

typedef __attribute__((ext_vector_type(4))) float f32x4;
typedef __attribute__((ext_vector_type(8))) short bf16x8;

__device__ __forceinline__ unsigned short f2bf(float f) {
    unsigned int u = __float_as_uint(f);
    unsigned int r = (u + 0x7fffu + ((u >> 16) & 1u)) >> 16;
    return (unsigned short)r;
}
__device__ __forceinline__ float bf2f(unsigned short s) {
    return __uint_as_float((unsigned int)s << 16);
}

// =============== prep: fold BN into conv weights, transpose GCN weights ===============
__global__ void k_prep(const float* __restrict__ c1w, const float* __restrict__ c1b,
                       const float* __restrict__ g1, const float* __restrict__ b1,
                       const float* __restrict__ c2w, const float* __restrict__ c2b,
                       const float* __restrict__ g2, const float* __restrict__ b2,
                       const float* __restrict__ c3w, const float* __restrict__ c3b,
                       const float* __restrict__ g3, const float* __restrict__ b3,
                       const float* __restrict__ w1, const float* __restrict__ w2,
                       float* __restrict__ wf1, float* __restrict__ bf1,
                       float* __restrict__ wf2t, float* __restrict__ bf2c,
                       float* __restrict__ wf3t, float* __restrict__ bf3c,
                       unsigned short* __restrict__ wt1, unsigned short* __restrict__ wt2) {
    int tid = threadIdx.x;
    const float rs = rsqrtf(1.f + EPS_);
    for (int i = tid; i < C1_ * K1_; i += 256) { int c = i / K1_; wf1[i] = c1w[i] * g1[c] * rs; }
    if (tid < C1_) bf1[tid] = c1b[tid] * g1[tid] * rs + b1[tid];
    // wf2t[(c1*M2+m)*16 + c2]
    for (int i = tid; i < C1_ * M2_ * C2_; i += 256) {
        int c2 = i & 15, cm = i >> 4;
        int c1 = cm / M2_, m = cm % M2_;
        float s = 0.f;
        for (int k = 0; k < K2_; ++k) { int d = m - k; if (d >= 0 && d <= 3) s += c2w[(c2 * C1_ + c1) * K2_ + k]; }
        wf2t[i] = s * g2[c2] * rs * 0.25f;
    }
    if (tid < C2_) bf2c[tid] = c2b[tid] * g2[tid] * rs + b2[tid];
    // wf3t[(c2*M3+m)*32 + c3]
    for (int i = tid; i < C3_ * C2_ * M3_; i += 256) {
        int c3 = i & 31, cm = i >> 5;
        int c2 = cm / M3_, m = cm % M3_;
        float s = 0.f;
        for (int k = 0; k < K3_; ++k) { int d = m - k; if (d >= 0 && d <= 3) s += c3w[(c3 * C2_ + c2) * K3_ + k]; }
        wf3t[i] = s * g3[c3] * rs * 0.25f;
    }
    if (tid < C3_) bf3c[tid] = c3b[tid] * g3[tid] * rs + b3[tid];
    // wt1[d][c] = gcn1_w[c][d]  (128x32 bf16)
    for (int i = tid; i < C3_ * D_; i += 256) { int d = i >> 5, c = i & 31; wt1[i] = f2bf(w1[c * D_ + d]); }
    // wt2[d2][d1] = gcn2_w[d1][d2]  (128x128 bf16)
    for (int i = tid; i < D_ * D_; i += 256) { int d2 = i >> 7, d1 = i & 127; wt2[i] = f2bf(w2[d1 * D_ + d2]); }
}

// ======================= positional MLP =======================
__global__ void k_pe(const float* __restrict__ pos, const float* __restrict__ w1,
                     const float* __restrict__ b1, const float* __restrict__ w2,
                     const float* __restrict__ b2, float* __restrict__ pe) {
    __shared__ float hid[8][32];
    int tid = threadIdx.x;
    int c = tid & 31, nl = tid >> 5;
    int n = blockIdx.x * 8 + nl;
    float p0 = pos[n * 3 + 0], p1 = pos[n * 3 + 1], p2 = pos[n * 3 + 2];
    float h = fmaxf(p0 * w1[c] + p1 * w1[32 + c] + p2 * w1[64 + c] + b1[c], 0.f);
    hid[nl][c] = h;
    __syncthreads();
    float o = b2[c];
#pragma unroll
    for (int cc = 0; cc < 32; ++cc) o += hid[nl][cc] * w2[cc * 32 + c];
    pe[n * 32 + c] = o;
}

// ======================= conv1 + bn1 + relu (bf16 out) =======================
__global__ __launch_bounds__(256) void k_conv1(const float* __restrict__ x,
        const float* __restrict__ wf1, const float* __restrict__ bf1,
        unsigned short* __restrict__ h1) {
    __shared__ float xs[256 + K1_ - 1];
    __shared__ float wl[C1_ * K1_];
    __shared__ float bl[C1_];
    int bid = blockIdx.x;
    int n = bid >> 2, t0 = (bid & 3) << 8;
    int tid = threadIdx.x;
    for (int i = tid; i < 256 + K1_ - 1; i += 256) {
        int gi = t0 - (K1_ / 2) + i;
        xs[i] = (gi >= 0 && gi < T_) ? x[n * T_ + gi] : 0.f;
    }
    for (int i = tid; i < C1_ * K1_; i += 256) wl[i] = wf1[i];
    if (tid < C1_) bl[tid] = bf1[tid];
    __syncthreads();
#pragma unroll
    for (int c = 0; c < C1_; ++c) {
        float acc = bl[c];
#pragma unroll
        for (int k = 0; k < K1_; ++k) acc += wl[c * K1_ + k] * xs[tid + k];
        h1[((size_t)n * C1_ + c) * T_ + t0 + tid] = f2bf(fmaxf(acc, 0.f));
    }
}

// ===== conv2+bn2+pool4+relu: phase-split LDS (conflict-free), h2 padded [n][16][256] =====
__global__ __launch_bounds__(256) void k_conv2(const unsigned short* __restrict__ h1,
        const float* __restrict__ wf2t, const float* __restrict__ bf2c,
        unsigned short* __restrict__ h2) {
    __shared__ float xs[4][C1_][256];        // 32 KB, phase-split: x[c1][4u+ph] -> xs[ph][c1][u]
    __shared__ float wl[C1_ * M2_ * C2_];    // 9.2 KB
    __shared__ float bl[C2_];
    int n = blockIdx.x, tid = threadIdx.x;
    const bf16x8* src = (const bf16x8*)(h1 + (size_t)n * C1_ * T_);
#pragma unroll
    for (int it = 0; it < 4; ++it) {
        int idx = tid + 256 * it;            // 1024 granules of 8 bf16
        bf16x8 v = src[idx];
        int c1 = idx >> 7;
        int u0 = (idx & 127) * 2;
#pragma unroll
        for (int j = 0; j < 8; ++j) xs[j & 3][c1][u0 + (j >> 2)] = bf2f((unsigned short)v[j]);
    }
    for (int i = tid; i < C1_ * M2_ * C2_; i += 256) wl[i] = wf2t[i];
    if (tid < C2_) bl[tid] = bf2c[tid];
    __syncthreads();
    if (tid < 252) {
        f32x4 acc[4];
#pragma unroll
        for (int c = 0; c < 4; ++c)
#pragma unroll
            for (int j = 0; j < 4; ++j) acc[c][j] = bl[c * 4 + j];
#pragma unroll
        for (int c1 = 0; c1 < C1_; ++c1) {
#pragma unroll
            for (int m = 0; m < M2_; ++m) {
                float xv = xs[m & 3][c1][tid + (m >> 2)];
                const f32x4* wp = (const f32x4*)&wl[(c1 * M2_ + m) * C2_];
#pragma unroll
                for (int c = 0; c < 4; ++c) acc[c] += xv * wp[c];
            }
        }
#pragma unroll
        for (int c2 = 0; c2 < C2_; ++c2)
            h2[((size_t)n * C2_ + c2) * 256 + tid] = f2bf(fmaxf(acc[c2 >> 2][c2 & 3], 0.f));
    }
}

// ==== conv3+bn3+pool4+relu + pe: thread=(t, cgroup of 8), h3 [n][t][c] bf16 ====
__global__ __launch_bounds__(256) void k_conv3(const unsigned short* __restrict__ h2,
        const float* __restrict__ wf3t, const float* __restrict__ bf3c,
        const float* __restrict__ pe, unsigned short* __restrict__ h3) {
    __shared__ float xs[C2_][256];           // 16 KB
    __shared__ float wl[C2_ * M3_ * C3_];    // 20.5 KB, [(c2*M3+m)*32 + c3]
    __shared__ float blB[C3_], pes[C3_];
    int n = blockIdx.x, tid = threadIdx.x;
    const bf16x8* src = (const bf16x8*)(h2 + (size_t)n * C2_ * 256);
#pragma unroll
    for (int it = 0; it < 2; ++it) {
        int idx = tid + 256 * it;            // 512 granules
        bf16x8 v = src[idx];
        int c2 = idx >> 5;
        int t8 = (idx & 31) * 8;
#pragma unroll
        for (int j = 0; j < 8; ++j) xs[c2][t8 + j] = bf2f((unsigned short)v[j]);
    }
    for (int i = tid; i < C2_ * M3_ * C3_; i += 256) wl[i] = wf3t[i];
    if (tid < C3_) { blB[tid] = bf3c[tid]; pes[tid] = pe[n * C3_ + tid]; }
    __syncthreads();
    if (tid < T2_ * 4) {
        int t = tid >> 2, cg = tid & 3;
        const f32x4* bl4 = (const f32x4*)&blB[cg * 8];
        f32x4 a0 = bl4[0], a1 = bl4[1];
#pragma unroll
        for (int c2 = 0; c2 < C2_; ++c2) {
#pragma unroll
            for (int m = 0; m < M3_; ++m) {
                float xv = xs[c2][4 * t + m];
                const f32x4* wp = (const f32x4*)&wl[(c2 * M3_ + m) * C3_ + cg * 8];
                a0 += xv * wp[0];
                a1 += xv * wp[1];
            }
        }
        const f32x4* pe4 = (const f32x4*)&pes[cg * 8];
        f32x4 p0 = pe4[0], p1 = pe4[1];
        bf16x8 sv;
#pragma unroll
        for (int j = 0; j < 4; ++j) {
            sv[j]     = (short)f2bf(fmaxf(a0[j], 0.f) + p0[j]);
            sv[4 + j] = (short)f2bf(fmaxf(a1[j], 0.f) + p1[j]);
        }
        *(bf16x8*)(h3 + (size_t)n * H3E_ + t * C3_ + cg * 8) = sv;
    }
}

// ======================= graph CSR build =======================
__global__ void k_count(const int* __restrict__ ei, int* __restrict__ count) {
    int e = blockIdx.x * 256 + threadIdx.x;
    if (e < E_) atomicAdd(&count[ei[E_ + e]], 1);
}

__global__ void k_scan(const int* __restrict__ count, int* __restrict__ off,
                       float* __restrict__ dinv) {
    __shared__ int part[256];
    int tid = threadIdx.x;
    int loc[8];
    int s = 0;
    int base = tid * 8;
#pragma unroll
    for (int j = 0; j < 8; ++j) { loc[j] = count[base + j]; s += loc[j]; }
    part[tid] = s;
    __syncthreads();
    for (int o = 1; o < 256; o <<= 1) {
        int add = (tid >= o) ? part[tid - o] : 0;
        __syncthreads();
        part[tid] += add;
        __syncthreads();
    }
    int run = part[tid] - s;
#pragma unroll
    for (int j = 0; j < 8; ++j) {
        off[base + j] = run;
        run += loc[j];
        dinv[base + j] = rsqrtf((float)(loc[j] + 1));
    }
}

__global__ void k_fill(const int* __restrict__ ei, const int* __restrict__ off,
                       int* __restrict__ cur, int* __restrict__ csr) {
    int e = blockIdx.x * 256 + threadIdx.x;
    if (e < E_) {
        int d = ei[E_ + e];
        int p = atomicAdd(&cur[d], 1);
        csr[off[d] + p] = ei[e];
    }
}

// ====== gather aggregation, bf16 in / bf16 out, f32 accum, both dinv folded ======
template <int NG>   // granules of 8 bf16 per row
__global__ __launch_bounds__(256) void k_agg_bf(const unsigned short* __restrict__ h,
        const int* __restrict__ off, const int* __restrict__ cnt, const int* __restrict__ csr,
        const float* __restrict__ dinv, unsigned short* __restrict__ out) {
    constexpr int RPT = (NG + 255) / 256;
    int n = blockIdx.x, tid = threadIdx.x;
    float acc[RPT][8];
    float dn = dinv[n];
    const bf16x8* self = (const bf16x8*)(h + (size_t)n * NG * 8);
#pragma unroll
    for (int r = 0; r < RPT; ++r) {
        int q = tid + 256 * r;
        if (q < NG) {
            bf16x8 v = self[q];
#pragma unroll
            for (int j = 0; j < 8; ++j) acc[r][j] = dn * bf2f((unsigned short)v[j]);
        }
    }
    int st = off[n], c = cnt[n];
    for (int i = 0; i < c; ++i) {
        int sn = csr[st + i];
        float f = dinv[sn];
        const bf16x8* rowp = (const bf16x8*)(h + (size_t)sn * NG * 8);
#pragma unroll
        for (int r = 0; r < RPT; ++r) {
            int q = tid + 256 * r;
            if (q < NG) {
                bf16x8 v = rowp[q];
#pragma unroll
                for (int j = 0; j < 8; ++j) acc[r][j] += f * bf2f((unsigned short)v[j]);
            }
        }
    }
    bf16x8* o = (bf16x8*)(out + (size_t)n * NG * 8);
#pragma unroll
    for (int r = 0; r < RPT; ++r) {
        int q = tid + 256 * r;
        if (q < NG) {
            bf16x8 v;
#pragma unroll
            for (int j = 0; j < 8; ++j) v[j] = (short)f2bf(acc[r][j] * dn);
            o[q] = v;
        }
    }
}

// ====== flattened MFMA GEMM, K=32: out = relu(A@W1 + b), bf16 ======
// A [M][32], Bt [128][32] (= W1^T), out [M][128]
__global__ __launch_bounds__(256) void k_gemm_mfma1(const unsigned short* __restrict__ A,
        const unsigned short* __restrict__ Bt, const float* __restrict__ bias,
        unsigned short* __restrict__ Cout) {
    int blk = blockIdx.x;
    int wid = threadIdx.x >> 6, lane = threadIdx.x & 63;
    int wr = wid >> 1, wc = wid & 1;
    int row0 = blk * 128 + wr * 64;
    int col0 = wc * 64;
    int lrow = lane & 15, lk = lane >> 4;
    f32x4 acc[4][4];
#pragma unroll
    for (int m = 0; m < 4; ++m)
#pragma unroll
        for (int nn = 0; nn < 4; ++nn)
#pragma unroll
            for (int r = 0; r < 4; ++r) acc[m][nn][r] = 0.f;
    bf16x8 a[4], b[4];
#pragma unroll
    for (int m = 0; m < 4; ++m)
        a[m] = *(const bf16x8*)(A + ((size_t)(row0 + m * 16 + lrow)) * 32 + lk * 8);
#pragma unroll
    for (int nn = 0; nn < 4; ++nn)
        b[nn] = *(const bf16x8*)(Bt + ((size_t)(col0 + nn * 16 + lrow)) * 32 + lk * 8);
#pragma unroll
    for (int m = 0; m < 4; ++m)
#pragma unroll
        for (int nn = 0; nn < 4; ++nn)
            acc[m][nn] = __builtin_amdgcn_mfma_f32_16x16x32_bf16(a[m], b[nn], acc[m][nn], 0, 0, 0);
#pragma unroll
    for (int m = 0; m < 4; ++m) {
        int row_base = row0 + m * 16 + (lane >> 4) * 4;
#pragma unroll
        for (int nn = 0; nn < 4; ++nn) {
            int col = col0 + nn * 16 + (lane & 15);
            float bv = bias[col];
#pragma unroll
            for (int r = 0; r < 4; ++r)
                Cout[(size_t)(row_base + r) * D_ + col] = f2bf(fmaxf(acc[m][nn][r] + bv, 0.f));
        }
    }
}

// ====== flattened MFMA GEMM, K=128: out = relu(A@W2 + b), bf16 ======
__global__ __launch_bounds__(256) void k_gemm_mfma2(const unsigned short* __restrict__ A,
        const unsigned short* __restrict__ Bt, const float* __restrict__ bias,
        unsigned short* __restrict__ Cout) {
    int blk = blockIdx.x;
    int wid = threadIdx.x >> 6, lane = threadIdx.x & 63;
    int wr = wid >> 1, wc = wid & 1;
    int row0 = blk * 128 + wr * 64;
    int col0 = wc * 64;
    int lrow = lane & 15, lk = lane >> 4;
    f32x4 acc[4][4];
#pragma unroll
    for (int m = 0; m < 4; ++m)
#pragma unroll
        for (int nn = 0; nn < 4; ++nn)
#pragma unroll
            for (int r = 0; r < 4; ++r) acc[m][nn][r] = 0.f;
#pragma unroll
    for (int ks = 0; ks < 4; ++ks) {
        bf16x8 a[4], b[4];
#pragma unroll
        for (int m = 0; m < 4; ++m)
            a[m] = *(const bf16x8*)(A + ((size_t)(row0 + m * 16 + lrow)) * D_ + ks * 32 + lk * 8);
#pragma unroll
        for (int nn = 0; nn < 4; ++nn)
            b[nn] = *(const bf16x8*)(Bt + ((size_t)(col0 + nn * 16 + lrow)) * D_ + ks * 32 + lk * 8);
#pragma unroll
        for (int m = 0; m < 4; ++m)
#pragma unroll
            for (int nn = 0; nn < 4; ++nn)
                acc[m][nn] = __builtin_amdgcn_mfma_f32_16x16x32_bf16(a[m], b[nn], acc[m][nn], 0, 0, 0);
    }
#pragma unroll
    for (int m = 0; m < 4; ++m) {
        int row_base = row0 + m * 16 + (lane >> 4) * 4;
#pragma unroll
        for (int nn = 0; nn < 4; ++nn) {
            int col = col0 + nn * 16 + (lane & 15);
            float bv = bias[col];
#pragma unroll
            for (int r = 0; r < 4; ++r)
                Cout[(size_t)(row_base + r) * D_ + col] = f2bf(fmaxf(acc[m][nn][r] + bv, 0.f));
        }
    }
}

// ================= batch pooling =================
__global__ void k_cnt(const int* __restrict__ batch, int* __restrict__ cnt) {
    int n = blockIdx.x * 256 + threadIdx.x;
    if (n < N_) atomicAdd(&cnt[batch[n]], 1);
}

__global__ void k_pool(const unsigned short* __restrict__ h2f, const int* __restrict__ batch,
                       float* __restrict__ pooled) {
    __shared__ float accum[B_ * D_];
    int t = blockIdx.x;               // 0..60
    int chunk = blockIdx.y;           // 0..7
    int d = threadIdx.x;              // 0..127
    for (int i = d; i < B_ * D_; i += 128) accum[i] = 0.f;
    __syncthreads();
    int n0 = chunk * 256;
    for (int n = n0; n < n0 + 256; ++n) {
        float v = bf2f(h2f[(size_t)(n * T2_ + t) * D_ + d]);
        accum[batch[n] * D_ + d] += v;
    }
    __syncthreads();
    for (int b = 0; b < B_; ++b)
        atomicAdd(&pooled[(size_t)b * HGE_ + d * T2_ + t], accum[b * D_ + d]);
}

// ============== dense (7808x4) + log_softmax ==============
__global__ void k_final(const float* __restrict__ pooled, const int* __restrict__ cnt,
                        const float* __restrict__ dw, const float* __restrict__ db,
                        float* __restrict__ out) {
    __shared__ float red[4][256];
    int b = blockIdx.x, tid = threadIdx.x;
    float inv = 1.f / fmaxf((float)cnt[b], 1.f);
    float a0 = 0.f, a1 = 0.f, a2 = 0.f, a3 = 0.f;
    const float4* dw4 = (const float4*)dw;
    for (int f = tid; f < HGE_; f += 256) {
        float v = pooled[(size_t)b * HGE_ + f] * inv;
        float4 w = dw4[f];
        a0 += v * w.x; a1 += v * w.y; a2 += v * w.z; a3 += v * w.w;
    }
    red[0][tid] = a0; red[1][tid] = a1; red[2][tid] = a2; red[3][tid] = a3;
    __syncthreads();
    for (int off = 128; off > 0; off >>= 1) {
        if (tid < off)
            for (int j = 0; j < 4; ++j) red[j][tid] += red[j][tid + off];
        __syncthreads();
    }
    if (tid == 0) {
        float l[4];
        for (int j = 0; j < 4; ++j) l[j] = red[j][0] + db[j];
        float m = fmaxf(fmaxf(l[0], l[1]), fmaxf(l[2], l[3]));
        float s = expf(l[0] - m) + expf(l[1] - m) + expf(l[2] - m) + expf(l[3] - m);
        float ls = m + logf(s);
        for (int j = 0; j < 4; ++j) out[b * 4 + j] = l[j] - ls;
    }
}

// ======================= launch =======================
extern "C" void kernel_launch(void* const* d_in, const int* in_sizes, int n_in,
                              void* d_out, int out_size, void* d_ws, size_t ws_size,
                              hipStream_t stream) {
    const float* x       = (const float*)d_in[0];
    const float* pos     = (const float*)d_in[1];
    const float* conv1_w = (const float*)d_in[2];
    const float* conv1_b = (const float*)d_in[3];
    const float* bn1_g   = (const float*)d_in[4];
    const float* bn1_b   = (const float*)d_in[5];
    const float* conv2_w = (const float*)d_in[6];
    const float* conv2_b = (const float*)d_in[7];
    const float* bn2_g   = (const float*)d_in[8];
    const float* bn2_b   = (const float*)d_in[9];
    const float* conv3_w = (const float*)d_in[10];
    const float* conv3_b = (const float*)d_in[11];
    const float* bn3_g   = (const float*)d_in[12];
    const float* bn3_b   = (const float*)d_in[13];
    const float* pos_w1  = (const float*)d_in[14];
    const float* pos_b1  = (const float*)d_in[15];
    const float* pos_w2  = (const float*)d_in[16];
    const float* pos_b2  = (const float*)d_in[17];
    const float* gcn1_w  = (const float*)d_in[18];
    const float* gcn1_b  = (const float*)d_in[19];
    const float* gcn2_w  = (const float*)d_in[20];
    const float* gcn2_b  = (const float*)d_in[21];
    const float* dense_w = (const float*)d_in[22];
    const float* dense_b = (const float*)d_in[23];
    const int*   eidx    = (const int*)d_in[24];
    const int*   batch   = (const int*)d_in[25];
    float* out = (float*)d_out;
    char* ws = (char*)d_ws;

    size_t off = 0;
    auto alloc = [&](size_t bytes) { size_t o = off; off += (bytes + 255) & ~(size_t)255; return o; };
    size_t o_h1     = alloc((size_t)N_ * C1_ * T_ * 2);      // 33.5 MB bf16
    size_t o_h2     = alloc((size_t)N_ * C2_ * 256 * 2);     // 16.8 MB bf16 (padded rows)
    size_t o_h3     = alloc((size_t)N_ * H3E_ * 2);          // 8 MB bf16
    size_t o_agg1   = alloc((size_t)N_ * H3E_ * 2);          // 8 MB bf16
    size_t o_hg1    = alloc((size_t)N_ * HGE_ * 2);          // 32 MB bf16
    size_t o_agg2   = alloc((size_t)N_ * HGE_ * 2);          // 32 MB bf16
    size_t o_h2f    = alloc((size_t)N_ * HGE_ * 2);          // 32 MB bf16
    size_t o_pe     = alloc((size_t)N_ * C3_ * 4);
    size_t o_pooled = alloc((size_t)B_ * HGE_ * 4);
    size_t o_count  = alloc((size_t)N_ * 4);
    size_t o_off    = alloc((size_t)N_ * 4);
    size_t o_cur    = alloc((size_t)N_ * 4);
    size_t o_dinv   = alloc((size_t)N_ * 4);
    size_t o_csr    = alloc((size_t)E_ * 4);
    size_t o_cnt    = alloc((size_t)B_ * 4);
    size_t o_wf1    = alloc((size_t)C1_ * K1_ * 4);
    size_t o_bf1    = alloc((size_t)C1_ * 4);
    size_t o_wf2t   = alloc((size_t)C1_ * M2_ * C2_ * 4);
    size_t o_bf2c   = alloc((size_t)C2_ * 4);
    size_t o_wf3t   = alloc((size_t)C2_ * M3_ * C3_ * 4);
    size_t o_bf3c   = alloc((size_t)C3_ * 4);
    size_t o_wt1    = alloc((size_t)C3_ * D_ * 2);
    size_t o_wt2    = alloc((size_t)D_ * D_ * 2);

    unsigned short* h1   = (unsigned short*)(ws + o_h1);
    unsigned short* h2   = (unsigned short*)(ws + o_h2);
    unsigned short* h3   = (unsigned short*)(ws + o_h3);
    unsigned short* agg1 = (unsigned short*)(ws + o_agg1);
    unsigned short* hg1  = (unsigned short*)(ws + o_hg1);
    unsigned short* agg2 = (unsigned short*)(ws + o_agg2);
    unsigned short* h2f  = (unsigned short*)(ws + o_h2f);
    float* pe     = (float*)(ws + o_pe);
    float* pooled = (float*)(ws + o_pooled);
    int*   count  = (int*)(ws + o_count);
    int*   offs   = (int*)(ws + o_off);
    int*   cur    = (int*)(ws + o_cur);
    float* dinv   = (float*)(ws + o_dinv);
    int*   csr    = (int*)(ws + o_csr);
    int*   cnt    = (int*)(ws + o_cnt);
    float* wf1    = (float*)(ws + o_wf1);
    float* bf1    = (float*)(ws + o_bf1);
    float* wf2t   = (float*)(ws + o_wf2t);
    float* bf2c   = (float*)(ws + o_bf2c);
    float* wf3t   = (float*)(ws + o_wf3t);
    float* bf3c   = (float*)(ws + o_bf3c);
    unsigned short* wt1 = (unsigned short*)(ws + o_wt1);
    unsigned short* wt2 = (unsigned short*)(ws + o_wt2);

    hipMemsetAsync(count, 0, (size_t)N_ * 4, stream);
    hipMemsetAsync(cur, 0, (size_t)N_ * 4, stream);
    hipMemsetAsync(cnt, 0, (size_t)B_ * 4, stream);
    hipMemsetAsync(pooled, 0, (size_t)B_ * HGE_ * 4, stream);

    k_prep<<<1, 256, 0, stream>>>(conv1_w, conv1_b, bn1_g, bn1_b,
                                  conv2_w, conv2_b, bn2_g, bn2_b,
                                  conv3_w, conv3_b, bn3_g, bn3_b,
                                  gcn1_w, gcn2_w,
                                  wf1, bf1, wf2t, bf2c, wf3t, bf3c, wt1, wt2);
    k_pe<<<N_ / 8, 256, 0, stream>>>(pos, pos_w1, pos_b1, pos_w2, pos_b2, pe);
    k_conv1<<<N_ * 4, 256, 0, stream>>>(x, wf1, bf1, h1);
    k_conv2<<<N_, 256, 0, stream>>>(h1, wf2t, bf2c, h2);
    k_conv3<<<N_, 256, 0, stream>>>(h2, wf3t, bf3c, pe, h3);

    k_count<<<E_ / 256, 256, 0, stream>>>(eidx, count);
    k_scan<<<1, 256, 0, stream>>>(count, offs, dinv);
    k_fill<<<E_ / 256, 256, 0, stream>>>(eidx, offs, cur, csr);
    k_cnt<<<N_ / 256, 256, 0, stream>>>(batch, cnt);

    k_agg_bf<H3E_ / 8><<<N_, 256, 0, stream>>>(h3, offs, count, csr, dinv, agg1);
    k_gemm_mfma1<<<M_ / 128, 256, 0, stream>>>(agg1, wt1, gcn1_b, hg1);
    k_agg_bf<HGE_ / 8><<<N_, 256, 0, stream>>>(hg1, offs, count, csr, dinv, agg2);
    k_gemm_mfma2<<<M_ / 128, 256, 0, stream>>>(agg2, wt2, gcn2_b, h2f);

    k_pool<<<dim3(T2_, 8), 128, 0, stream>>>(h2f, batch, pooled);
    k_final<<<B_, 256, 0, stream>>>(pooled, cnt, dense_w, dense_b, out);
}

// Round 3
// 382.597 us; speedup vs baseline: 4.2121x; 1.3727x over previous
//
#include <hip/hip_runtime.h>
#include <math.h>

// ---- problem constants ----
constexpr int N_  = 2048;
constexpr int T_  = 1024;
constexpr int E_  = 16384;
constexpr int B_  = 32;
constexpr int C1_ = 8,  C2_ = 16, C3_ = 32;
constexpr int K1_ = 25, K2_ = 15, K3_ = 7;
constexpr int T2_ = 61;           // conv3+pool output length
constexpr int D_  = 128;
constexpr float EPS_ = 1e-5f;
constexpr int M2_ = K2_ + 3;      // 18 fused taps (conv2 ⊗ pool4)
constexpr int M3_ = K3_ + 3;      // 10 fused taps (conv3 ⊗ pool4)
constexpr int H3E_ = T2_ * C3_;   // 1952 elems/node after conv stack
constexpr int HGE_ = T2_ * D_;    // 7808 elems/node in GCN space
constexpr int M_   = N_ * T2_;    // 124928 flattened GEMM rows (= 976*128)

typedef __attribute__((ext_vector_type(4))) float f32x4;
typedef __attribute__((ext_vector_type(8))) short bf16x8;

__device__ __forceinline__ unsigned short f2bf(float f) {
    unsigned int u = __float_as_uint(f);
    unsigned int r = (u + 0x7fffu + ((u >> 16) & 1u)) >> 16;
    return (unsigned short)r;
}
__device__ __forceinline__ float bf2f(unsigned short s) {
    return __uint_as_float((unsigned int)s << 16);
}

// =============== prep: fold BN into conv weights, transpose GCN weights ===============
__global__ void k_prep(const float* __restrict__ c1w, const float* __restrict__ c1b,
                       const float* __restrict__ g1, const float* __restrict__ b1,
                       const float* __restrict__ c2w, const float* __restrict__ c2b,
                       const float* __restrict__ g2, const float* __restrict__ b2,
                       const float* __restrict__ c3w, const float* __restrict__ c3b,
                       const float* __restrict__ g3, const float* __restrict__ b3,
                       const float* __restrict__ w1, const float* __restrict__ w2,
                       float* __restrict__ wf1t, float* __restrict__ bf1,
                       float* __restrict__ wf2t, float* __restrict__ bf2c,
                       float* __restrict__ wf3t, float* __restrict__ bf3c,
                       unsigned short* __restrict__ wt1, unsigned short* __restrict__ wt2) {
    int tid = threadIdx.x;
    const float rs = rsqrtf(1.f + EPS_);
    // wf1t[k*8 + c] = conv1_w[c][k] * bnfold
    for (int i = tid; i < C1_ * K1_; i += 256) {
        int k = i >> 3, c = i & 7;
        wf1t[i] = c1w[c * K1_ + k] * g1[c] * rs;
    }
    if (tid < C1_) bf1[tid] = c1b[tid] * g1[tid] * rs + b1[tid];
    // wf2t[(c1*M2+m)*16 + c2]
    for (int i = tid; i < C1_ * M2_ * C2_; i += 256) {
        int c2 = i & 15, cm = i >> 4;
        int c1 = cm / M2_, m = cm % M2_;
        float s = 0.f;
        for (int k = 0; k < K2_; ++k) { int d = m - k; if (d >= 0 && d <= 3) s += c2w[(c2 * C1_ + c1) * K2_ + k]; }
        wf2t[i] = s * g2[c2] * rs * 0.25f;
    }
    if (tid < C2_) bf2c[tid] = c2b[tid] * g2[tid] * rs + b2[tid];
    // wf3t[(c2*M3+m)*32 + c3]
    for (int i = tid; i < C3_ * C2_ * M3_; i += 256) {
        int c3 = i & 31, cm = i >> 5;
        int c2 = cm / M3_, m = cm % M3_;
        float s = 0.f;
        for (int k = 0; k < K3_; ++k) { int d = m - k; if (d >= 0 && d <= 3) s += c3w[(c3 * C2_ + c2) * K3_ + k]; }
        wf3t[i] = s * g3[c3] * rs * 0.25f;
    }
    if (tid < C3_) bf3c[tid] = c3b[tid] * g3[tid] * rs + b3[tid];
    // wt1[d][c] = gcn1_w[c][d]  (128x32 bf16)
    for (int i = tid; i < C3_ * D_; i += 256) { int d = i >> 5, c = i & 31; wt1[i] = f2bf(w1[c * D_ + d]); }
    // wt2[d2][d1] = gcn2_w[d1][d2]  (128x128 bf16)
    for (int i = tid; i < D_ * D_; i += 256) { int d2 = i >> 7, d1 = i & 127; wt2[i] = f2bf(w2[d1 * D_ + d2]); }
}

// ======================= positional MLP =======================
__global__ void k_pe(const float* __restrict__ pos, const float* __restrict__ w1,
                     const float* __restrict__ b1, const float* __restrict__ w2,
                     const float* __restrict__ b2, float* __restrict__ pe) {
    __shared__ float hid[8][32];
    int tid = threadIdx.x;
    int c = tid & 31, nl = tid >> 5;
    int n = blockIdx.x * 8 + nl;
    float p0 = pos[n * 3 + 0], p1 = pos[n * 3 + 1], p2 = pos[n * 3 + 2];
    float h = fmaxf(p0 * w1[c] + p1 * w1[32 + c] + p2 * w1[64 + c] + b1[c], 0.f);
    hid[nl][c] = h;
    __syncthreads();
    float o = b2[c];
#pragma unroll
    for (int cc = 0; cc < 32; ++cc) o += hid[nl][cc] * w2[cc * 32 + c];
    pe[n * 32 + c] = o;
}

// ===== fused conv1+bn1+relu -> conv2+bn2+pool4+relu, h2 padded [n][16][256] bf16 =====
// conv1 output lives only in phase-split LDS: x1[c][4u+ph] -> xs[ph][c][u] (pad 258)
__global__ __launch_bounds__(256) void k_conv12(const float* __restrict__ x,
        const float* __restrict__ wf1t, const float* __restrict__ bf1,
        const float* __restrict__ wf2t, const float* __restrict__ bf2c,
        unsigned short* __restrict__ h2) {
    __shared__ float xin[T_ + K1_ - 1];      // 1048 f32, halo-padded input row
    __shared__ float xs[4][C1_][258];        // 33 KB phase-split conv1 output
    __shared__ float wl1[C1_ * K1_];         // 200
    __shared__ float wl2[C1_ * M2_ * C2_];   // 2304
    __shared__ float bl1[C1_], bl2[C2_];
    int n = blockIdx.x, tid = threadIdx.x;
    for (int i = tid; i < T_ + K1_ - 1; i += 256) {
        int gi = i - (K1_ / 2);
        xin[i] = (gi >= 0 && gi < T_) ? x[n * T_ + gi] : 0.f;
    }
    for (int i = tid; i < C1_ * K1_; i += 256) wl1[i] = wf1t[i];
    for (int i = tid; i < C1_ * M2_ * C2_; i += 256) wl2[i] = wf2t[i];
    if (tid < C1_) bl1[tid] = bf1[tid];
    if (tid < C2_) bl2[tid] = bf2c[tid];
    __syncthreads();
    // conv1: thread computes positions t = tid + 256*it, all 8 channels
#pragma unroll
    for (int it = 0; it < 4; ++it) {
        int t = tid + 256 * it;
        float a[C1_];
#pragma unroll
        for (int c = 0; c < C1_; ++c) a[c] = bl1[c];
#pragma unroll
        for (int k = 0; k < K1_; ++k) {
            float xv = xin[t + k];
            const f32x4* wp = (const f32x4*)&wl1[k * C1_];
            f32x4 w0 = wp[0], w1v = wp[1];
#pragma unroll
            for (int j = 0; j < 4; ++j) { a[j] += w0[j] * xv; a[4 + j] += w1v[j] * xv; }
        }
        int ph = t & 3, u = t >> 2;
#pragma unroll
        for (int c = 0; c < C1_; ++c) xs[ph][c][u] = fmaxf(a[c], 0.f);
    }
    __syncthreads();
    // conv2 (fused 18-tap), position p = tid < 252
    if (tid < 252) {
        f32x4 acc[4];
#pragma unroll
        for (int c = 0; c < 4; ++c)
#pragma unroll
            for (int j = 0; j < 4; ++j) acc[c][j] = bl2[c * 4 + j];
#pragma unroll
        for (int c1 = 0; c1 < C1_; ++c1) {
#pragma unroll
            for (int m = 0; m < M2_; ++m) {
                float xv = xs[m & 3][c1][tid + (m >> 2)];
                const f32x4* wp = (const f32x4*)&wl2[(c1 * M2_ + m) * C2_];
#pragma unroll
                for (int c = 0; c < 4; ++c) acc[c] += xv * wp[c];
            }
        }
#pragma unroll
        for (int c2 = 0; c2 < C2_; ++c2)
            h2[((size_t)n * C2_ + c2) * 256 + tid] = f2bf(fmaxf(acc[c2 >> 2][c2 & 3], 0.f));
    }
}

// ==== conv3+bn3+pool4+relu + pe: thread=(t, cgroup of 8), h3 [n][t][c] bf16 ====
__global__ __launch_bounds__(256) void k_conv3(const unsigned short* __restrict__ h2,
        const float* __restrict__ wf3t, const float* __restrict__ bf3c,
        const float* __restrict__ pe, unsigned short* __restrict__ h3) {
    __shared__ float xs[C2_][256];           // 16 KB
    __shared__ float wl[C2_ * M3_ * C3_];    // 20.5 KB, [(c2*M3+m)*32 + c3]
    __shared__ float blB[C3_], pes[C3_];
    int n = blockIdx.x, tid = threadIdx.x;
    const bf16x8* src = (const bf16x8*)(h2 + (size_t)n * C2_ * 256);
#pragma unroll
    for (int it = 0; it < 2; ++it) {
        int idx = tid + 256 * it;            // 512 granules
        bf16x8 v = src[idx];
        int c2 = idx >> 5;
        int t8 = (idx & 31) * 8;
#pragma unroll
        for (int j = 0; j < 8; ++j) xs[c2][t8 + j] = bf2f((unsigned short)v[j]);
    }
    for (int i = tid; i < C2_ * M3_ * C3_; i += 256) wl[i] = wf3t[i];
    if (tid < C3_) { blB[tid] = bf3c[tid]; pes[tid] = pe[n * C3_ + tid]; }
    __syncthreads();
    if (tid < T2_ * 4) {
        int t = tid >> 2, cg = tid & 3;
        const f32x4* bl4 = (const f32x4*)&blB[cg * 8];
        f32x4 a0 = bl4[0], a1 = bl4[1];
#pragma unroll
        for (int c2 = 0; c2 < C2_; ++c2) {
#pragma unroll
            for (int m = 0; m < M3_; ++m) {
                float xv = xs[c2][4 * t + m];
                const f32x4* wp = (const f32x4*)&wl[(c2 * M3_ + m) * C3_ + cg * 8];
                a0 += xv * wp[0];
                a1 += xv * wp[1];
            }
        }
        const f32x4* pe4 = (const f32x4*)&pes[cg * 8];
        f32x4 p0 = pe4[0], p1 = pe4[1];
        bf16x8 sv;
#pragma unroll
        for (int j = 0; j < 4; ++j) {
            sv[j]     = (short)f2bf(fmaxf(a0[j], 0.f) + p0[j]);
            sv[4 + j] = (short)f2bf(fmaxf(a1[j], 0.f) + p1[j]);
        }
        *(bf16x8*)(h3 + (size_t)n * H3E_ + t * C3_ + cg * 8) = sv;
    }
}

// ======================= graph CSR build =======================
__global__ void k_count(const int* __restrict__ ei, int* __restrict__ count) {
    int e = blockIdx.x * 256 + threadIdx.x;
    if (e < E_) atomicAdd(&count[ei[E_ + e]], 1);
}

__global__ void k_scan(const int* __restrict__ count, int* __restrict__ off,
                       float* __restrict__ dinv) {
    __shared__ int part[256];
    int tid = threadIdx.x;
    int loc[8];
    int s = 0;
    int base = tid * 8;
#pragma unroll
    for (int j = 0; j < 8; ++j) { loc[j] = count[base + j]; s += loc[j]; }
    part[tid] = s;
    __syncthreads();
    for (int o = 1; o < 256; o <<= 1) {
        int add = (tid >= o) ? part[tid - o] : 0;
        __syncthreads();
        part[tid] += add;
        __syncthreads();
    }
    int run = part[tid] - s;
#pragma unroll
    for (int j = 0; j < 8; ++j) {
        off[base + j] = run;
        run += loc[j];
        dinv[base + j] = rsqrtf((float)(loc[j] + 1));
    }
}

__global__ void k_fill(const int* __restrict__ ei, const int* __restrict__ off,
                       int* __restrict__ cur, int* __restrict__ csr) {
    int e = blockIdx.x * 256 + threadIdx.x;
    if (e < E_) {
        int d = ei[E_ + e];
        int p = atomicAdd(&cur[d], 1);
        csr[off[d] + p] = ei[e];
    }
}

// ====== gather aggregation, bf16 in / bf16 out, f32 accum, both dinv folded ======
template <int NG>   // granules of 8 bf16 per row
__global__ __launch_bounds__(256) void k_agg_bf(const unsigned short* __restrict__ h,
        const int* __restrict__ off, const int* __restrict__ cnt, const int* __restrict__ csr,
        const float* __restrict__ dinv, unsigned short* __restrict__ out) {
    constexpr int RPT = (NG + 255) / 256;
    int n = blockIdx.x, tid = threadIdx.x;
    float acc[RPT][8];
    float dn = dinv[n];
    const bf16x8* self = (const bf16x8*)(h + (size_t)n * NG * 8);
#pragma unroll
    for (int r = 0; r < RPT; ++r) {
        int q = tid + 256 * r;
        if (q < NG) {
            bf16x8 v = self[q];
#pragma unroll
            for (int j = 0; j < 8; ++j) acc[r][j] = dn * bf2f((unsigned short)v[j]);
        }
    }
    int st = off[n], c = cnt[n];
    for (int i = 0; i < c; ++i) {
        int sn = csr[st + i];
        float f = dinv[sn];
        const bf16x8* rowp = (const bf16x8*)(h + (size_t)sn * NG * 8);
#pragma unroll
        for (int r = 0; r < RPT; ++r) {
            int q = tid + 256 * r;
            if (q < NG) {
                bf16x8 v = rowp[q];
#pragma unroll
                for (int j = 0; j < 8; ++j) acc[r][j] += f * bf2f((unsigned short)v[j]);
            }
        }
    }
    bf16x8* o = (bf16x8*)(out + (size_t)n * NG * 8);
#pragma unroll
    for (int r = 0; r < RPT; ++r) {
        int q = tid + 256 * r;
        if (q < NG) {
            bf16x8 v;
#pragma unroll
            for (int j = 0; j < 8; ++j) v[j] = (short)f2bf(acc[r][j] * dn);
            o[q] = v;
        }
    }
}

// ====== flattened MFMA GEMM, K=32: out = relu(A@W1 + b), bf16 ======
__global__ __launch_bounds__(256) void k_gemm_mfma1(const unsigned short* __restrict__ A,
        const unsigned short* __restrict__ Bt, const float* __restrict__ bias,
        unsigned short* __restrict__ Cout) {
    int blk = blockIdx.x;
    int wid = threadIdx.x >> 6, lane = threadIdx.x & 63;
    int wr = wid >> 1, wc = wid & 1;
    int row0 = blk * 128 + wr * 64;
    int col0 = wc * 64;
    int lrow = lane & 15, lk = lane >> 4;
    f32x4 acc[4][4];
#pragma unroll
    for (int m = 0; m < 4; ++m)
#pragma unroll
        for (int nn = 0; nn < 4; ++nn)
#pragma unroll
            for (int r = 0; r < 4; ++r) acc[m][nn][r] = 0.f;
    bf16x8 a[4], b[4];
#pragma unroll
    for (int m = 0; m < 4; ++m)
        a[m] = *(const bf16x8*)(A + ((size_t)(row0 + m * 16 + lrow)) * 32 + lk * 8);
#pragma unroll
    for (int nn = 0; nn < 4; ++nn)
        b[nn] = *(const bf16x8*)(Bt + ((size_t)(col0 + nn * 16 + lrow)) * 32 + lk * 8);
#pragma unroll
    for (int m = 0; m < 4; ++m)
#pragma unroll
        for (int nn = 0; nn < 4; ++nn)
            acc[m][nn] = __builtin_amdgcn_mfma_f32_16x16x32_bf16(a[m], b[nn], acc[m][nn], 0, 0, 0);
#pragma unroll
    for (int m = 0; m < 4; ++m) {
        int row_base = row0 + m * 16 + (lane >> 4) * 4;
#pragma unroll
        for (int nn = 0; nn < 4; ++nn) {
            int col = col0 + nn * 16 + (lane & 15);
            float bv = bias[col];
#pragma unroll
            for (int r = 0; r < 4; ++r)
                Cout[(size_t)(row_base + r) * D_ + col] = f2bf(fmaxf(acc[m][nn][r] + bv, 0.f));
        }
    }
}

// ====== flattened MFMA GEMM K=128 + FUSED dense projection epilogue ======
// out never materialized: relu(A@W2+b) row (n,t), col d -> logits_acc[batch[n]][j]
//   += v * dense_w[(d*61+t)*4 + j]
__global__ __launch_bounds__(256) void k_gemm_mfma2f(const unsigned short* __restrict__ A,
        const unsigned short* __restrict__ Bt, const float* __restrict__ bias,
        const float* __restrict__ dw, const int* __restrict__ batch,
        float* __restrict__ logits_acc) {
    __shared__ float bacc[B_ * 4];
    int tid = threadIdx.x;
    if (tid < B_ * 4) bacc[tid] = 0.f;
    int blk = blockIdx.x;
    int wid = tid >> 6, lane = tid & 63;
    int wr = wid >> 1, wc = wid & 1;
    int row0 = blk * 128 + wr * 64;
    int col0 = wc * 64;
    int lrow = lane & 15, lk = lane >> 4;
    f32x4 acc[4][4];
#pragma unroll
    for (int m = 0; m < 4; ++m)
#pragma unroll
        for (int nn = 0; nn < 4; ++nn)
#pragma unroll
            for (int r = 0; r < 4; ++r) acc[m][nn][r] = 0.f;
#pragma unroll
    for (int ks = 0; ks < 4; ++ks) {
        bf16x8 a[4], b[4];
#pragma unroll
        for (int m = 0; m < 4; ++m)
            a[m] = *(const bf16x8*)(A + ((size_t)(row0 + m * 16 + lrow)) * D_ + ks * 32 + lk * 8);
#pragma unroll
        for (int nn = 0; nn < 4; ++nn)
            b[nn] = *(const bf16x8*)(Bt + ((size_t)(col0 + nn * 16 + lrow)) * D_ + ks * 32 + lk * 8);
#pragma unroll
        for (int m = 0; m < 4; ++m)
#pragma unroll
            for (int nn = 0; nn < 4; ++nn)
                acc[m][nn] = __builtin_amdgcn_mfma_f32_16x16x32_bf16(a[m], b[nn], acc[m][nn], 0, 0, 0);
    }
    __syncthreads();   // bacc zeroing visible before atomics
    // per-thread projection; rows increase monotonically -> flush on batch change
    int cur_b = -1;
    f32x4 sacc = {0.f, 0.f, 0.f, 0.f};
#pragma unroll
    for (int m = 0; m < 4; ++m) {
#pragma unroll
        for (int r = 0; r < 4; ++r) {
            int row = row0 + m * 16 + lk * 4 + r;
            int n = row / T2_;
            int t = row - n * T2_;
            int b = batch[n];
            f32x4 s = {0.f, 0.f, 0.f, 0.f};
#pragma unroll
            for (int nn = 0; nn < 4; ++nn) {
                int col = col0 + nn * 16 + lrow;
                float v = fmaxf(acc[m][nn][r] + bias[col], 0.f);
                f32x4 w = *(const f32x4*)(dw + (size_t)(col * T2_ + t) * 4);
                s += v * w;
            }
            if (b != cur_b) {
                if (cur_b >= 0) {
#pragma unroll
                    for (int j = 0; j < 4; ++j) atomicAdd(&bacc[cur_b * 4 + j], sacc[j]);
                }
                cur_b = b;
                sacc = s;
            } else {
                sacc += s;
            }
        }
    }
    if (cur_b >= 0) {
#pragma unroll
        for (int j = 0; j < 4; ++j) atomicAdd(&bacc[cur_b * 4 + j], sacc[j]);
    }
    __syncthreads();
    if (tid < B_ * 4) {
        float v = bacc[tid];
        if (v != 0.f) atomicAdd(&logits_acc[tid], v);
    }
}

// ================= batch counts =================
__global__ void k_cnt(const int* __restrict__ batch, int* __restrict__ cnt) {
    int n = blockIdx.x * 256 + threadIdx.x;
    if (n < N_) atomicAdd(&cnt[batch[n]], 1);
}

// ============== tiny final: /cnt, +db, log_softmax ==============
__global__ void k_final2(const float* __restrict__ acc, const int* __restrict__ cnt,
                         const float* __restrict__ db, float* __restrict__ out) {
    int b = threadIdx.x;
    if (b < B_) {
        float inv = 1.f / fmaxf((float)cnt[b], 1.f);
        float l[4];
#pragma unroll
        for (int j = 0; j < 4; ++j) l[j] = acc[b * 4 + j] * inv + db[j];
        float m = fmaxf(fmaxf(l[0], l[1]), fmaxf(l[2], l[3]));
        float s = expf(l[0] - m) + expf(l[1] - m) + expf(l[2] - m) + expf(l[3] - m);
        float ls = m + logf(s);
#pragma unroll
        for (int j = 0; j < 4; ++j) out[b * 4 + j] = l[j] - ls;
    }
}

// ======================= launch =======================
extern "C" void kernel_launch(void* const* d_in, const int* in_sizes, int n_in,
                              void* d_out, int out_size, void* d_ws, size_t ws_size,
                              hipStream_t stream) {
    const float* x       = (const float*)d_in[0];
    const float* pos     = (const float*)d_in[1];
    const float* conv1_w = (const float*)d_in[2];
    const float* conv1_b = (const float*)d_in[3];
    const float* bn1_g   = (const float*)d_in[4];
    const float* bn1_b   = (const float*)d_in[5];
    const float* conv2_w = (const float*)d_in[6];
    const float* conv2_b = (const float*)d_in[7];
    const float* bn2_g   = (const float*)d_in[8];
    const float* bn2_b   = (const float*)d_in[9];
    const float* conv3_w = (const float*)d_in[10];
    const float* conv3_b = (const float*)d_in[11];
    const float* bn3_g   = (const float*)d_in[12];
    const float* bn3_b   = (const float*)d_in[13];
    const float* pos_w1  = (const float*)d_in[14];
    const float* pos_b1  = (const float*)d_in[15];
    const float* pos_w2  = (const float*)d_in[16];
    const float* pos_b2  = (const float*)d_in[17];
    const float* gcn1_w  = (const float*)d_in[18];
    const float* gcn1_b  = (const float*)d_in[19];
    const float* gcn2_w  = (const float*)d_in[20];
    const float* gcn2_b  = (const float*)d_in[21];
    const float* dense_w = (const float*)d_in[22];
    const float* dense_b = (const float*)d_in[23];
    const int*   eidx    = (const int*)d_in[24];
    const int*   batch   = (const int*)d_in[25];
    float* out = (float*)d_out;
    char* ws = (char*)d_ws;

    size_t off = 0;
    auto alloc = [&](size_t bytes) { size_t o = off; off += (bytes + 255) & ~(size_t)255; return o; };
    size_t o_h2     = alloc((size_t)N_ * C2_ * 256 * 2);     // 16.8 MB bf16 (padded rows)
    size_t o_h3     = alloc((size_t)N_ * H3E_ * 2);          // 8 MB bf16
    size_t o_agg1   = alloc((size_t)N_ * H3E_ * 2);          // 8 MB bf16
    size_t o_hg1    = alloc((size_t)N_ * HGE_ * 2);          // 32 MB bf16
    size_t o_agg2   = alloc((size_t)N_ * HGE_ * 2);          // 32 MB bf16
    size_t o_pe     = alloc((size_t)N_ * C3_ * 4);
    size_t o_lacc   = alloc((size_t)B_ * 4 * 4);
    size_t o_count  = alloc((size_t)N_ * 4);
    size_t o_off    = alloc((size_t)N_ * 4);
    size_t o_cur    = alloc((size_t)N_ * 4);
    size_t o_dinv   = alloc((size_t)N_ * 4);
    size_t o_csr    = alloc((size_t)E_ * 4);
    size_t o_cnt    = alloc((size_t)B_ * 4);
    size_t o_wf1t   = alloc((size_t)C1_ * K1_ * 4);
    size_t o_bf1    = alloc((size_t)C1_ * 4);
    size_t o_wf2t   = alloc((size_t)C1_ * M2_ * C2_ * 4);
    size_t o_bf2c   = alloc((size_t)C2_ * 4);
    size_t o_wf3t   = alloc((size_t)C2_ * M3_ * C3_ * 4);
    size_t o_bf3c   = alloc((size_t)C3_ * 4);
    size_t o_wt1    = alloc((size_t)C3_ * D_ * 2);
    size_t o_wt2    = alloc((size_t)D_ * D_ * 2);

    unsigned short* h2   = (unsigned short*)(ws + o_h2);
    unsigned short* h3   = (unsigned short*)(ws + o_h3);
    unsigned short* agg1 = (unsigned short*)(ws + o_agg1);
    unsigned short* hg1  = (unsigned short*)(ws + o_hg1);
    unsigned short* agg2 = (unsigned short*)(ws + o_agg2);
    float* pe     = (float*)(ws + o_pe);
    float* lacc   = (float*)(ws + o_lacc);
    int*   count  = (int*)(ws + o_count);
    int*   offs   = (int*)(ws + o_off);
    int*   cur    = (int*)(ws + o_cur);
    float* dinv   = (float*)(ws + o_dinv);
    int*   csr    = (int*)(ws + o_csr);
    int*   cnt    = (int*)(ws + o_cnt);
    float* wf1t   = (float*)(ws + o_wf1t);
    float* bf1    = (float*)(ws + o_bf1);
    float* wf2t   = (float*)(ws + o_wf2t);
    float* bf2c   = (float*)(ws + o_bf2c);
    float* wf3t   = (float*)(ws + o_wf3t);
    float* bf3c   = (float*)(ws + o_bf3c);
    unsigned short* wt1 = (unsigned short*)(ws + o_wt1);
    unsigned short* wt2 = (unsigned short*)(ws + o_wt2);

    hipMemsetAsync(count, 0, (size_t)N_ * 4, stream);
    hipMemsetAsync(cur, 0, (size_t)N_ * 4, stream);
    hipMemsetAsync(cnt, 0, (size_t)B_ * 4, stream);
    hipMemsetAsync(lacc, 0, (size_t)B_ * 4 * 4, stream);

    k_prep<<<1, 256, 0, stream>>>(conv1_w, conv1_b, bn1_g, bn1_b,
                                  conv2_w, conv2_b, bn2_g, bn2_b,
                                  conv3_w, conv3_b, bn3_g, bn3_b,
                                  gcn1_w, gcn2_w,
                                  wf1t, bf1, wf2t, bf2c, wf3t, bf3c, wt1, wt2);
    k_pe<<<N_ / 8, 256, 0, stream>>>(pos, pos_w1, pos_b1, pos_w2, pos_b2, pe);
    k_conv12<<<N_, 256, 0, stream>>>(x, wf1t, bf1, wf2t, bf2c, h2);
    k_conv3<<<N_, 256, 0, stream>>>(h2, wf3t, bf3c, pe, h3);

    k_count<<<E_ / 256, 256, 0, stream>>>(eidx, count);
    k_scan<<<1, 256, 0, stream>>>(count, offs, dinv);
    k_fill<<<E_ / 256, 256, 0, stream>>>(eidx, offs, cur, csr);
    k_cnt<<<N_ / 256, 256, 0, stream>>>(batch, cnt);

    k_agg_bf<H3E_ / 8><<<N_, 256, 0, stream>>>(h3, offs, count, csr, dinv, agg1);
    k_gemm_mfma1<<<M_ / 128, 256, 0, stream>>>(agg1, wt1, gcn1_b, hg1);
    k_agg_bf<HGE_ / 8><<<N_, 256, 0, stream>>>(hg1, offs, count, csr, dinv, agg2);
    k_gemm_mfma2f<<<M_ / 128, 256, 0, stream>>>(agg2, wt2, gcn2_b, dense_w, batch, lacc);

    k_final2<<<1, 64, 0, stream>>>(lacc, cnt, dense_b, out);
}

// Round 4
// 312.631 us; speedup vs baseline: 5.1548x; 1.2238x over previous
//
#include <hip/hip_runtime.h>
#include <math.h>

// ---- problem constants ----
constexpr int N_  = 2048;
constexpr int T_  = 1024;
constexpr int E_  = 16384;
constexpr int B_  = 32;
constexpr int C1_ = 8,  C2_ = 16, C3_ = 32;
constexpr int K1_ = 25, K2_ = 15, K3_ = 7;
constexpr int T2_ = 61;           // conv3+pool output length
constexpr int D_  = 128;
constexpr float EPS_ = 1e-5f;
constexpr int M2_ = K2_ + 3;      // 18 fused taps (conv2 ⊗ pool4)
constexpr int M3_ = K3_ + 3;      // 10 fused taps (conv3 ⊗ pool4)
constexpr int H3E_ = T2_ * C3_;   // 1952 elems/node after conv stack
constexpr int HGE_ = T2_ * D_;    // 7808 elems/node in GCN space
constexpr int M_   = N_ * T2_;    // 124928 flattened GEMM rows (= 976*128)

typedef __attribute__((ext_vector_type(4))) float f32x4;
typedef __attribute__((ext_vector_type(8))) short bf16x8;

__device__ __forceinline__ unsigned short f2bf(float f) {
    unsigned int u = __float_as_uint(f);
    unsigned int r = (u + 0x7fffu + ((u >> 16) & 1u)) >> 16;
    return (unsigned short)r;
}
__device__ __forceinline__ float bf2f(unsigned short s) {
    return __uint_as_float((unsigned int)s << 16);
}

// =============== prep: fold BN, build MFMA-ready weights, zero counters ===============
__global__ void k_prep(const float* __restrict__ c1w, const float* __restrict__ c1b,
                       const float* __restrict__ g1, const float* __restrict__ b1,
                       const float* __restrict__ c2w, const float* __restrict__ c2b,
                       const float* __restrict__ g2, const float* __restrict__ b2,
                       const float* __restrict__ c3w, const float* __restrict__ c3b,
                       const float* __restrict__ g3, const float* __restrict__ b3,
                       const float* __restrict__ w1, const float* __restrict__ w2,
                       float* __restrict__ wf1t, float* __restrict__ bf1,
                       unsigned short* __restrict__ wB2, float* __restrict__ bf2c,
                       float* __restrict__ wf3t, float* __restrict__ bf3c,
                       unsigned short* __restrict__ wt1, unsigned short* __restrict__ wt2,
                       int* __restrict__ count, int* __restrict__ cur,
                       int* __restrict__ cnt, float* __restrict__ lacc) {
    int tid = threadIdx.x;
    const float rs = rsqrtf(1.f + EPS_);
    // zero counters
    for (int i = tid; i < N_; i += 256) { count[i] = 0; cur[i] = 0; }
    if (tid < B_) cnt[tid] = 0;
    if (tid < B_ * 4) lacc[tid] = 0.f;
    // wf1t[k*8 + c] = conv1_w[c][k] * bnfold
    for (int i = tid; i < C1_ * K1_; i += 256) {
        int k = i >> 3, c = i & 7;
        wf1t[i] = c1w[c * K1_ + k] * g1[c] * rs;
    }
    if (tid < C1_) bf1[tid] = c1b[tid] * g1[tid] * rs + b1[tid];
    // wB2[g][c2][ph*8+c1] bf16: fused conv2 taps m=4g+ph (0 if m>=18), B-operand layout
    for (int i = tid; i < 5 * C2_ * 32; i += 256) {
        int g = i >> 9, rem = i & 511;
        int c2 = rem >> 5, k32 = rem & 31;
        int ph = k32 >> 3, c1 = k32 & 7;
        int m = 4 * g + ph;
        float s = 0.f;
        if (m < M2_) {
            for (int k = 0; k < K2_; ++k) { int d = m - k; if (d >= 0 && d <= 3) s += c2w[(c2 * C1_ + c1) * K2_ + k]; }
            s *= g2[c2] * rs * 0.25f;
        }
        wB2[i] = f2bf(s);
    }
    if (tid < C2_) bf2c[tid] = c2b[tid] * g2[tid] * rs + b2[tid];
    // wf3t[(c2*M3+m)*32 + c3] f32 fused conv3 taps
    for (int i = tid; i < C3_ * C2_ * M3_; i += 256) {
        int c3 = i & 31, cm = i >> 5;
        int c2 = cm / M3_, m = cm % M3_;
        float s = 0.f;
        for (int k = 0; k < K3_; ++k) { int d = m - k; if (d >= 0 && d <= 3) s += c3w[(c3 * C2_ + c2) * K3_ + k]; }
        wf3t[i] = s * g3[c3] * rs * 0.25f;
    }
    if (tid < C3_) bf3c[tid] = c3b[tid] * g3[tid] * rs + b3[tid];
    // wt1[d][c] = gcn1_w[c][d]  (128x32 bf16)
    for (int i = tid; i < C3_ * D_; i += 256) { int d = i >> 5, c = i & 31; wt1[i] = f2bf(w1[c * D_ + d]); }
    // wt2[d2][d1] = gcn2_w[d1][d2]  (128x128 bf16)
    for (int i = tid; i < D_ * D_; i += 256) { int d2 = i >> 7, d1 = i & 127; wt2[i] = f2bf(w2[d1 * D_ + d2]); }
}

// ======================= positional MLP =======================
__global__ void k_pe(const float* __restrict__ pos, const float* __restrict__ w1,
                     const float* __restrict__ b1, const float* __restrict__ w2,
                     const float* __restrict__ b2, float* __restrict__ pe) {
    __shared__ float hid[8][32];
    int tid = threadIdx.x;
    int c = tid & 31, nl = tid >> 5;
    int n = blockIdx.x * 8 + nl;
    float p0 = pos[n * 3 + 0], p1 = pos[n * 3 + 1], p2 = pos[n * 3 + 2];
    float h = fmaxf(p0 * w1[c] + p1 * w1[32 + c] + p2 * w1[64 + c] + b1[c], 0.f);
    hid[nl][c] = h;
    __syncthreads();
    float o = b2[c];
#pragma unroll
    for (int cc = 0; cc < 32; ++cc) o += hid[nl][cc] * w2[cc * 32 + c];
    pe[n * 32 + c] = o;
}

// ========== mega-fused conv stack: conv1 VALU -> conv2 MFMA -> conv3 VALU ==========
// xs2: conv1 out, MFMA-A-ready: row u (80B = 40 bf16), entry [u][ph*8+c1] = conv1(t=4u+ph, c1)
// conv2: A[p][g*32+ph*8+c1] = xs2[p+g][ph*8+c1]; 5 K-steps; C -> h2s[c2][257]
// conv3: VALU from h2s; wl3 overlaid on xs2 after conv2.
__global__ __launch_bounds__(256) void k_conv123(const float* __restrict__ x,
        const float* __restrict__ wf1t, const float* __restrict__ bf1,
        const unsigned short* __restrict__ wB2g, const float* __restrict__ bf2c,
        const float* __restrict__ wf3t, const float* __restrict__ bf3c,
        const float* __restrict__ pe, unsigned short* __restrict__ h3) {
    __shared__ __align__(16) float xin[T_ + K1_ - 1];        // 1048
    __shared__ __align__(16) float wl1[C1_ * K1_];           // 200
    __shared__ __align__(16) unsigned short wB2[5 * 16 * 32];// 2560 bf16
    __shared__ float bl1[C1_], bl2[C2_], bl3[C3_], pes[C3_];
    __shared__ __align__(16) unsigned short xs2[260 * 40];   // 20.8KB; overlaid by wl3 (20.5KB)
    __shared__ __align__(16) float h2s[C2_ * 257];           // 16.4KB
    float* wl3 = (float*)xs2;
    int n = blockIdx.x, tid = threadIdx.x;
    // ---- stage ----
    for (int i = tid; i < T_ + K1_ - 1; i += 256) {
        int gi = i - (K1_ / 2);
        xin[i] = (gi >= 0 && gi < T_) ? x[n * T_ + gi] : 0.f;
    }
    if (tid < C1_ * K1_) wl1[tid] = wf1t[tid];
    for (int i = tid; i < 320; i += 256)
        ((bf16x8*)wB2)[i] = ((const bf16x8*)wB2g)[i];
    if (tid < C1_) bl1[tid] = bf1[tid];
    if (tid < C2_) bl2[tid] = bf2c[tid];
    if (tid < C3_) { bl3[tid] = bf3c[tid]; pes[tid] = pe[n * C3_ + tid]; }
    __syncthreads();
    // ---- conv1 (f32 VALU), write bf16 fragments ----
#pragma unroll
    for (int it = 0; it < 4; ++it) {
        int t = tid + 256 * it;
        float a[C1_];
#pragma unroll
        for (int c = 0; c < C1_; ++c) a[c] = bl1[c];
#pragma unroll
        for (int k = 0; k < K1_; ++k) {
            float xv = xin[t + k];
            const f32x4* wp = (const f32x4*)&wl1[k * C1_];
            f32x4 w0 = wp[0], w1v = wp[1];
#pragma unroll
            for (int j = 0; j < 4; ++j) { a[j] += w0[j] * xv; a[4 + j] += w1v[j] * xv; }
        }
        int u = t >> 2, ph = t & 3;
        bf16x8 sv;
#pragma unroll
        for (int c = 0; c < C1_; ++c) sv[c] = (short)f2bf(fmaxf(a[c], 0.f));
        *(bf16x8*)&xs2[u * 40 + ph * 8] = sv;
    }
    __syncthreads();
    // ---- conv2 via MFMA: 4 M-tiles per wave, 5 K-steps, N=16 ----
    {
        int wid = tid >> 6, lane = tid & 63;
        int lrow = lane & 15, lk = lane >> 4;
        bf16x8 bfr[5];
#pragma unroll
        for (int g = 0; g < 5; ++g)
            bfr[g] = *(const bf16x8*)&wB2[g * 512 + lrow * 32 + lk * 8];
#pragma unroll
        for (int mt = 0; mt < 4; ++mt) {
            int p0 = (wid * 4 + mt) * 16;
            f32x4 c4 = {0.f, 0.f, 0.f, 0.f};
#pragma unroll
            for (int g = 0; g < 5; ++g) {
                bf16x8 af = *(const bf16x8*)&xs2[(p0 + lrow + g) * 40 + lk * 8];
                c4 = __builtin_amdgcn_mfma_f32_16x16x32_bf16(af, bfr[g], c4, 0, 0, 0);
            }
            int c2 = lrow;
            float bb = bl2[c2];
#pragma unroll
            for (int r = 0; r < 4; ++r) {
                int p = p0 + lk * 4 + r;
                if (p < 252) h2s[c2 * 257 + p] = fmaxf(c4[r] + bb, 0.f);
            }
        }
    }
    __syncthreads();
    // ---- load conv3 weights into xs2 overlay ----
    for (int i = tid; i < C2_ * M3_ * C3_; i += 256) wl3[i] = wf3t[i];
    __syncthreads();
    // ---- conv3 (VALU) + pe, write h3 [n][t][c] bf16 ----
    if (tid < T2_ * 4) {
        int t = tid >> 2, cg = tid & 3;
        const f32x4* bl4 = (const f32x4*)&bl3[cg * 8];
        f32x4 a0 = bl4[0], a1 = bl4[1];
#pragma unroll
        for (int c2 = 0; c2 < C2_; ++c2) {
#pragma unroll
            for (int m = 0; m < M3_; ++m) {
                float xv = h2s[c2 * 257 + 4 * t + m];
                const f32x4* wp = (const f32x4*)&wl3[(c2 * M3_ + m) * C3_ + cg * 8];
                a0 += xv * wp[0];
                a1 += xv * wp[1];
            }
        }
        const f32x4* pe4 = (const f32x4*)&pes[cg * 8];
        f32x4 p0 = pe4[0], p1 = pe4[1];
        bf16x8 sv;
#pragma unroll
        for (int j = 0; j < 4; ++j) {
            sv[j]     = (short)f2bf(fmaxf(a0[j], 0.f) + p0[j]);
            sv[4 + j] = (short)f2bf(fmaxf(a1[j], 0.f) + p1[j]);
        }
        *(bf16x8*)(h3 + (size_t)n * H3E_ + t * C3_ + cg * 8) = sv;
    }
}

// ======================= graph CSR build =======================
__global__ void k_countcnt(const int* __restrict__ ei, const int* __restrict__ batch,
                           int* __restrict__ count, int* __restrict__ cnt) {
    int idx = blockIdx.x * 256 + threadIdx.x;
    if (idx < E_) atomicAdd(&count[ei[E_ + idx]], 1);
    if (idx < N_) atomicAdd(&cnt[batch[idx]], 1);
}

__global__ void k_scan(const int* __restrict__ count, int* __restrict__ off,
                       float* __restrict__ dinv) {
    __shared__ int part[256];
    int tid = threadIdx.x;
    int loc[8];
    int s = 0;
    int base = tid * 8;
#pragma unroll
    for (int j = 0; j < 8; ++j) { loc[j] = count[base + j]; s += loc[j]; }
    part[tid] = s;
    __syncthreads();
    for (int o = 1; o < 256; o <<= 1) {
        int add = (tid >= o) ? part[tid - o] : 0;
        __syncthreads();
        part[tid] += add;
        __syncthreads();
    }
    int run = part[tid] - s;
#pragma unroll
    for (int j = 0; j < 8; ++j) {
        off[base + j] = run;
        run += loc[j];
        dinv[base + j] = rsqrtf((float)(loc[j] + 1));
    }
}

__global__ void k_fill(const int* __restrict__ ei, const int* __restrict__ off,
                       int* __restrict__ cur, int* __restrict__ csr) {
    int e = blockIdx.x * 256 + threadIdx.x;
    if (e < E_) {
        int d = ei[E_ + e];
        int p = atomicAdd(&cur[d], 1);
        csr[off[d] + p] = ei[e];
    }
}

// ====== gather aggregation for layer 1 (bf16 in/out, f32 accum, both dinv folded) ======
template <int NG>
__global__ __launch_bounds__(256) void k_agg_bf(const unsigned short* __restrict__ h,
        const int* __restrict__ off, const int* __restrict__ cnt, const int* __restrict__ csr,
        const float* __restrict__ dinv, unsigned short* __restrict__ out) {
    int n = blockIdx.x, tid = threadIdx.x;
    float acc[8];
    float dn = dinv[n];
    const bf16x8* self = (const bf16x8*)(h + (size_t)n * NG * 8);
    if (tid < NG) {
        bf16x8 v = self[tid];
#pragma unroll
        for (int j = 0; j < 8; ++j) acc[j] = dn * bf2f((unsigned short)v[j]);
    }
    int st = off[n], c = cnt[n];
    for (int i = 0; i < c; ++i) {
        int sn = csr[st + i];
        float f = dinv[sn];
        if (tid < NG) {
            bf16x8 v = ((const bf16x8*)(h + (size_t)sn * NG * 8))[tid];
#pragma unroll
            for (int j = 0; j < 8; ++j) acc[j] += f * bf2f((unsigned short)v[j]);
        }
    }
    if (tid < NG) {
        bf16x8 v;
#pragma unroll
        for (int j = 0; j < 8; ++j) v[j] = (short)f2bf(acc[j] * dn);
        ((bf16x8*)(out + (size_t)n * NG * 8))[tid] = v;
    }
}

// ====== FUSED gemm1+agg2: agg2[n] = dinv[n] * sum_s dinv[s]*relu(agg1[s]@W1+b1) ======
// per-edge recompute of the tiny (61x32)@(32x128) GEMM keeps the gather table L2-resident.
__global__ __launch_bounds__(256) void k_agg_gemm1(const unsigned short* __restrict__ agg1,
        const unsigned short* __restrict__ wt1, const float* __restrict__ bias,
        const int* __restrict__ off, const int* __restrict__ cnt, const int* __restrict__ csr,
        const float* __restrict__ dinv, unsigned short* __restrict__ agg2) {
    int n = blockIdx.x, tid = threadIdx.x;
    int wid = tid >> 6, lane = tid & 63;
    int lrow = lane & 15, lk = lane >> 4;
    bf16x8 bfr[2];
    float bv[2];
#pragma unroll
    for (int nn = 0; nn < 2; ++nn) {
        int col = wid * 32 + nn * 16 + lrow;
        bfr[nn] = *(const bf16x8*)&wt1[col * 32 + lk * 8];
        bv[nn] = bias[col];
    }
    f32x4 acc[4][2];
#pragma unroll
    for (int mt = 0; mt < 4; ++mt)
#pragma unroll
        for (int nn = 0; nn < 2; ++nn) acc[mt][nn] = f32x4{0.f, 0.f, 0.f, 0.f};
    int st = off[n], c = cnt[n];
    for (int i = -1; i < c; ++i) {
        int s = (i < 0) ? n : csr[st + i];
        float f = dinv[s];
        const unsigned short* arow = agg1 + (size_t)s * H3E_;
        bf16x8 af[4];
#pragma unroll
        for (int mt = 0; mt < 4; ++mt)
            af[mt] = *(const bf16x8*)&arow[(mt * 16 + lrow) * 32 + lk * 8];
#pragma unroll
        for (int mt = 0; mt < 4; ++mt) {
#pragma unroll
            for (int nn = 0; nn < 2; ++nn) {
                f32x4 t4 = {0.f, 0.f, 0.f, 0.f};
                t4 = __builtin_amdgcn_mfma_f32_16x16x32_bf16(af[mt], bfr[nn], t4, 0, 0, 0);
#pragma unroll
                for (int r = 0; r < 4; ++r)
                    acc[mt][nn][r] += f * fmaxf(t4[r] + bv[nn], 0.f);
            }
        }
    }
    float dn = dinv[n];
    unsigned short* orow = agg2 + (size_t)n * HGE_;
#pragma unroll
    for (int mt = 0; mt < 4; ++mt) {
#pragma unroll
        for (int r = 0; r < 4; ++r) {
            int t = mt * 16 + lk * 4 + r;
            if (t < T2_) {
#pragma unroll
                for (int nn = 0; nn < 2; ++nn)
                    orow[t * D_ + wid * 32 + nn * 16 + lrow] = f2bf(acc[mt][nn][r] * dn);
            }
        }
    }
}

// ====== flattened MFMA GEMM K=128 + FUSED dense projection epilogue ======
__global__ __launch_bounds__(256) void k_gemm_mfma2f(const unsigned short* __restrict__ A,
        const unsigned short* __restrict__ Bt, const float* __restrict__ bias,
        const float* __restrict__ dw, const int* __restrict__ batch,
        float* __restrict__ logits_acc) {
    __shared__ float bacc[B_ * 4];
    int tid = threadIdx.x;
    if (tid < B_ * 4) bacc[tid] = 0.f;
    int blk = blockIdx.x;
    int wid = tid >> 6, lane = tid & 63;
    int wr = wid >> 1, wc = wid & 1;
    int row0 = blk * 128 + wr * 64;
    int col0 = wc * 64;
    int lrow = lane & 15, lk = lane >> 4;
    f32x4 acc[4][4];
#pragma unroll
    for (int m = 0; m < 4; ++m)
#pragma unroll
        for (int nn = 0; nn < 4; ++nn)
#pragma unroll
            for (int r = 0; r < 4; ++r) acc[m][nn][r] = 0.f;
#pragma unroll
    for (int ks = 0; ks < 4; ++ks) {
        bf16x8 a[4], b[4];
#pragma unroll
        for (int m = 0; m < 4; ++m)
            a[m] = *(const bf16x8*)(A + ((size_t)(row0 + m * 16 + lrow)) * D_ + ks * 32 + lk * 8);
#pragma unroll
        for (int nn = 0; nn < 4; ++nn)
            b[nn] = *(const bf16x8*)(Bt + ((size_t)(col0 + nn * 16 + lrow)) * D_ + ks * 32 + lk * 8);
#pragma unroll
        for (int m = 0; m < 4; ++m)
#pragma unroll
            for (int nn = 0; nn < 4; ++nn)
                acc[m][nn] = __builtin_amdgcn_mfma_f32_16x16x32_bf16(a[m], b[nn], acc[m][nn], 0, 0, 0);
    }
    __syncthreads();
    int cur_b = -1;
    f32x4 sacc = {0.f, 0.f, 0.f, 0.f};
#pragma unroll
    for (int m = 0; m < 4; ++m) {
#pragma unroll
        for (int r = 0; r < 4; ++r) {
            int row = row0 + m * 16 + lk * 4 + r;
            int n = row / T2_;
            int t = row - n * T2_;
            int b = batch[n];
            f32x4 s = {0.f, 0.f, 0.f, 0.f};
#pragma unroll
            for (int nn = 0; nn < 4; ++nn) {
                int col = col0 + nn * 16 + lrow;
                float v = fmaxf(acc[m][nn][r] + bias[col], 0.f);
                f32x4 w = *(const f32x4*)(dw + (size_t)(col * T2_ + t) * 4);
                s += v * w;
            }
            if (b != cur_b) {
                if (cur_b >= 0) {
#pragma unroll
                    for (int j = 0; j < 4; ++j) atomicAdd(&bacc[cur_b * 4 + j], sacc[j]);
                }
                cur_b = b;
                sacc = s;
            } else {
                sacc += s;
            }
        }
    }
    if (cur_b >= 0) {
#pragma unroll
        for (int j = 0; j < 4; ++j) atomicAdd(&bacc[cur_b * 4 + j], sacc[j]);
    }
    __syncthreads();
    if (tid < B_ * 4) {
        float v = bacc[tid];
        if (v != 0.f) atomicAdd(&logits_acc[tid], v);
    }
}

// ============== tiny final: /cnt, +db, log_softmax ==============
__global__ void k_final2(const float* __restrict__ acc, const int* __restrict__ cnt,
                         const float* __restrict__ db, float* __restrict__ out) {
    int b = threadIdx.x;
    if (b < B_) {
        float inv = 1.f / fmaxf((float)cnt[b], 1.f);
        float l[4];
#pragma unroll
        for (int j = 0; j < 4; ++j) l[j] = acc[b * 4 + j] * inv + db[j];
        float m = fmaxf(fmaxf(l[0], l[1]), fmaxf(l[2], l[3]));
        float s = expf(l[0] - m) + expf(l[1] - m) + expf(l[2] - m) + expf(l[3] - m);
        float ls = m + logf(s);
#pragma unroll
        for (int j = 0; j < 4; ++j) out[b * 4 + j] = l[j] - ls;
    }
}

// ======================= launch =======================
extern "C" void kernel_launch(void* const* d_in, const int* in_sizes, int n_in,
                              void* d_out, int out_size, void* d_ws, size_t ws_size,
                              hipStream_t stream) {
    const float* x       = (const float*)d_in[0];
    const float* pos     = (const float*)d_in[1];
    const float* conv1_w = (const float*)d_in[2];
    const float* conv1_b = (const float*)d_in[3];
    const float* bn1_g   = (const float*)d_in[4];
    const float* bn1_b   = (const float*)d_in[5];
    const float* conv2_w = (const float*)d_in[6];
    const float* conv2_b = (const float*)d_in[7];
    const float* bn2_g   = (const float*)d_in[8];
    const float* bn2_b   = (const float*)d_in[9];
    const float* conv3_w = (const float*)d_in[10];
    const float* conv3_b = (const float*)d_in[11];
    const float* bn3_g   = (const float*)d_in[12];
    const float* bn3_b   = (const float*)d_in[13];
    const float* pos_w1  = (const float*)d_in[14];
    const float* pos_b1  = (const float*)d_in[15];
    const float* pos_w2  = (const float*)d_in[16];
    const float* pos_b2  = (const float*)d_in[17];
    const float* gcn1_w  = (const float*)d_in[18];
    const float* gcn1_b  = (const float*)d_in[19];
    const float* gcn2_w  = (const float*)d_in[20];
    const float* gcn2_b  = (const float*)d_in[21];
    const float* dense_w = (const float*)d_in[22];
    const float* dense_b = (const float*)d_in[23];
    const int*   eidx    = (const int*)d_in[24];
    const int*   batch   = (const int*)d_in[25];
    float* out = (float*)d_out;
    char* ws = (char*)d_ws;

    size_t off = 0;
    auto alloc = [&](size_t bytes) { size_t o = off; off += (bytes + 255) & ~(size_t)255; return o; };
    size_t o_h3     = alloc((size_t)N_ * H3E_ * 2);              // 8 MB bf16
    size_t o_agg1   = alloc(((size_t)N_ * H3E_ + 2048) * 2);     // 8 MB bf16 (+slack for mt=3 overreads)
    size_t o_agg2   = alloc((size_t)N_ * HGE_ * 2);              // 32 MB bf16
    size_t o_pe     = alloc((size_t)N_ * C3_ * 4);
    size_t o_lacc   = alloc((size_t)B_ * 4 * 4);
    size_t o_count  = alloc((size_t)N_ * 4);
    size_t o_off    = alloc((size_t)N_ * 4);
    size_t o_cur    = alloc((size_t)N_ * 4);
    size_t o_dinv   = alloc((size_t)N_ * 4);
    size_t o_csr    = alloc((size_t)E_ * 4);
    size_t o_cnt    = alloc((size_t)B_ * 4);
    size_t o_wf1t   = alloc((size_t)C1_ * K1_ * 4);
    size_t o_bf1    = alloc((size_t)C1_ * 4);
    size_t o_wB2    = alloc((size_t)5 * C2_ * 32 * 2);
    size_t o_bf2c   = alloc((size_t)C2_ * 4);
    size_t o_wf3t   = alloc((size_t)C2_ * M3_ * C3_ * 4);
    size_t o_bf3c   = alloc((size_t)C3_ * 4);
    size_t o_wt1    = alloc((size_t)C3_ * D_ * 2);
    size_t o_wt2    = alloc((size_t)D_ * D_ * 2);

    unsigned short* h3   = (unsigned short*)(ws + o_h3);
    unsigned short* agg1 = (unsigned short*)(ws + o_agg1);
    unsigned short* agg2 = (unsigned short*)(ws + o_agg2);
    float* pe     = (float*)(ws + o_pe);
    float* lacc   = (float*)(ws + o_lacc);
    int*   count  = (int*)(ws + o_count);
    int*   offs   = (int*)(ws + o_off);
    int*   cur    = (int*)(ws + o_cur);
    float* dinv   = (float*)(ws + o_dinv);
    int*   csr    = (int*)(ws + o_csr);
    int*   cnt    = (int*)(ws + o_cnt);
    float* wf1t   = (float*)(ws + o_wf1t);
    float* bf1    = (float*)(ws + o_bf1);
    unsigned short* wB2 = (unsigned short*)(ws + o_wB2);
    float* bf2c   = (float*)(ws + o_bf2c);
    float* wf3t   = (float*)(ws + o_wf3t);
    float* bf3c   = (float*)(ws + o_bf3c);
    unsigned short* wt1 = (unsigned short*)(ws + o_wt1);
    unsigned short* wt2 = (unsigned short*)(ws + o_wt2);

    k_prep<<<1, 256, 0, stream>>>(conv1_w, conv1_b, bn1_g, bn1_b,
                                  conv2_w, conv2_b, bn2_g, bn2_b,
                                  conv3_w, conv3_b, bn3_g, bn3_b,
                                  gcn1_w, gcn2_w,
                                  wf1t, bf1, wB2, bf2c, wf3t, bf3c, wt1, wt2,
                                  count, cur, cnt, lacc);
    k_pe<<<N_ / 8, 256, 0, stream>>>(pos, pos_w1, pos_b1, pos_w2, pos_b2, pe);
    k_countcnt<<<E_ / 256, 256, 0, stream>>>(eidx, batch, count, cnt);
    k_scan<<<1, 256, 0, stream>>>(count, offs, dinv);
    k_fill<<<E_ / 256, 256, 0, stream>>>(eidx, offs, cur, csr);

    k_conv123<<<N_, 256, 0, stream>>>(x, wf1t, bf1, wB2, bf2c, wf3t, bf3c, pe, h3);

    k_agg_bf<H3E_ / 8><<<N_, 256, 0, stream>>>(h3, offs, count, csr, dinv, agg1);
    k_agg_gemm1<<<N_, 256, 0, stream>>>(agg1, wt1, gcn1_b, offs, count, csr, dinv, agg2);
    k_gemm_mfma2f<<<M_ / 128, 256, 0, stream>>>(agg2, wt2, gcn2_b, dense_w, batch, lacc);

    k_final2<<<1, 64, 0, stream>>>(lacc, cnt, dense_b, out);
}